// Round 1
// baseline (19281.310 us; speedup 1.0000x reference)
//
#include <hip/hip_runtime.h>
#include <cstdint>
#include <cstddef>

#define NEG_SLOPE 0.2f

__device__ __forceinline__ void atomicMaxF(float* addr, float val) {
    if (val >= 0.0f) atomicMax((int*)addr, __float_as_int(val));
    else             atomicMin((unsigned int*)addr, __float_as_uint(val));
}

__global__ void k_fill(float* __restrict__ p, float v, int n) {
    int i = blockIdx.x * blockDim.x + threadIdx.x;
    if (i < n) p[i] = v;
}

// ---- layer 1: h_all[n, r*128+col] = sum_k X[n,k] * W_r[k,col] ----
__global__ void k_linear1(const float* __restrict__ X,
                          const float* __restrict__ W1,
                          const float* __restrict__ W2,
                          const float* __restrict__ W3,
                          float* __restrict__ h_all, int N) {
    __shared__ float Xs[16][64];
    int n0 = blockIdx.x * 16;
    for (int i = threadIdx.x; i < 16 * 64; i += blockDim.x) {
        int nl = i >> 6, k = i & 63;
        int n = n0 + nl;
        Xs[nl][k] = (n < N) ? X[(size_t)n * 64 + k] : 0.f;
    }
    __syncthreads();
    for (int idx = threadIdx.x; idx < 16 * 384; idx += blockDim.x) {
        int nl = idx / 384;
        int j  = idx - nl * 384;
        int n  = n0 + nl;
        if (n >= N) continue;
        int r = j >> 7, col = j & 127;
        const float* W = (r == 0) ? W1 : (r == 1) ? W2 : W3;
        float acc = 0.f;
        #pragma unroll
        for (int k = 0; k < 64; ++k) acc = fmaf(Xs[nl][k], W[k * 128 + col], acc);
        h_all[(size_t)n * 384 + j] = acc;
    }
}

// ---- per-node attention scores: s[n, r*8+h] = sum_c h[n,r,h,c]*a[h,c] ----
__global__ void k_scores1(const float* __restrict__ h_all,
                          const float* __restrict__ as1, const float* __restrict__ ad1,
                          const float* __restrict__ as2, const float* __restrict__ ad2,
                          const float* __restrict__ as3, const float* __restrict__ ad3,
                          float* __restrict__ s_src, float* __restrict__ s_dst, int N) {
    int id = blockIdx.x * blockDim.x + threadIdx.x;
    if (id >= N * 24) return;
    int n = id / 24;
    int rh = id - n * 24;
    int r = rh >> 3, head = rh & 7;
    const float* a_s = (r == 0) ? as1 : (r == 1) ? as2 : as3;
    const float* a_d = (r == 0) ? ad1 : (r == 1) ? ad2 : ad3;
    const float* hp = h_all + (size_t)n * 384 + r * 128 + head * 16;
    const float* ap_s = a_s + head * 16;
    const float* ap_d = a_d + head * 16;
    float ss = 0.f, sd = 0.f;
    #pragma unroll
    for (int c = 0; c < 16; ++c) {
        float hv = hp[c];
        ss = fmaf(hv, ap_s[c], ss);
        sd = fmaf(hv, ap_d[c], sd);
    }
    s_src[id] = ss;
    s_dst[id] = sd;
}

// ---- layer-1 edge pass A: segment max. thread = (edge, head), blockIdx.y = branch ----
__global__ void k_edge_max1(const int* __restrict__ A1, const int* __restrict__ A2,
                            const int* __restrict__ A3,
                            const float* __restrict__ s_src, const float* __restrict__ s_dst,
                            float* __restrict__ emax, int E, int N) {
    int tid = blockIdx.x * blockDim.x + threadIdx.x;
    int e = tid >> 3, h = tid & 7;
    if (e >= E + N) return;
    int r = blockIdx.y;
    const int* A = (r == 0) ? A1 : (r == 1) ? A2 : A3;
    int src, dst;
    if (e < E) { src = A[e]; dst = A[E + e]; }
    else       { src = dst = e - E; }
    float v = s_src[(size_t)src * 24 + r * 8 + h] + s_dst[(size_t)dst * 24 + r * 8 + h];
    v = (v >= 0.f) ? v : NEG_SLOPE * v;
    atomicMaxF(&emax[(size_t)dst * 24 + r * 8 + h], v);
}

// ---- layer-1 edge pass B: denom += ex; acc += ex * h[src] ----
__global__ void k_edge_acc1(const int* __restrict__ A1, const int* __restrict__ A2,
                            const int* __restrict__ A3,
                            const float* __restrict__ s_src, const float* __restrict__ s_dst,
                            const float* __restrict__ emax,
                            const float* __restrict__ h_all,
                            float* __restrict__ denom, float* __restrict__ acc,
                            int E, int N) {
    int tid = blockIdx.x * blockDim.x + threadIdx.x;
    int e = tid >> 3, h = tid & 7;
    if (e >= E + N) return;
    int r = blockIdx.y;
    const int* A = (r == 0) ? A1 : (r == 1) ? A2 : A3;
    int src, dst;
    if (e < E) { src = A[e]; dst = A[E + e]; }
    else       { src = dst = e - E; }
    float v = s_src[(size_t)src * 24 + r * 8 + h] + s_dst[(size_t)dst * 24 + r * 8 + h];
    v = (v >= 0.f) ? v : NEG_SLOPE * v;
    float m = emax[(size_t)dst * 24 + r * 8 + h];
    float ex = __expf(v - m);
    atomicAdd(&denom[(size_t)dst * 24 + r * 8 + h], ex);
    const float* hs = h_all + (size_t)src * 384 + r * 128 + h * 16;
    float* ap = acc + (size_t)dst * 384 + r * 128 + h * 16;
    #pragma unroll
    for (int c = 0; c < 16; c += 4) {
        float4 hv = *reinterpret_cast<const float4*>(hs + c);
        atomicAdd(ap + c + 0, ex * hv.x);
        atomicAdd(ap + c + 1, ex * hv.y);
        atomicAdd(ap + c + 2, ex * hv.z);
        atomicAdd(ap + c + 3, ex * hv.w);
    }
}

// ---- layer-1 normalize + bias + relu -> Xc (overwrites h_all) ----
__global__ void k_norm1(const float* __restrict__ acc, const float* __restrict__ denom,
                        const float* __restrict__ b1, const float* __restrict__ b2,
                        const float* __restrict__ b3,
                        float* __restrict__ Xc, int N) {
    int id = blockIdx.x * blockDim.x + threadIdx.x;
    if (id >= N * 384) return;
    int n = id / 384;
    int j = id - n * 384;
    int r = j >> 7;
    int head = (j >> 4) & 7;
    const float* b = (r == 0) ? b1 : (r == 1) ? b2 : b3;
    float d = denom[(size_t)n * 24 + r * 8 + head] + 1e-16f;
    float v = acc[id] / d + b[j & 127];
    Xc[id] = (v > 0.f) ? v : 0.f;
}

// ---- layer 2 linear: one wave per node, 3 branch dots over 384 ----
__global__ void k_linear2(const float* __restrict__ Xc,
                          const float* __restrict__ W1, const float* __restrict__ W2,
                          const float* __restrict__ W3,
                          float* __restrict__ h2, int N) {
    int gid = blockIdx.x * blockDim.x + threadIdx.x;
    int wave = gid >> 6;
    int lane = gid & 63;
    if (wave >= N) return;
    const float* xp = Xc + (size_t)wave * 384;
    float s0 = 0.f, s1 = 0.f, s2 = 0.f;
    #pragma unroll
    for (int j0 = 0; j0 < 384; j0 += 64) {
        float x = xp[j0 + lane];
        s0 = fmaf(x, W1[j0 + lane], s0);
        s1 = fmaf(x, W2[j0 + lane], s1);
        s2 = fmaf(x, W3[j0 + lane], s2);
    }
    #pragma unroll
    for (int off = 32; off > 0; off >>= 1) {
        s0 += __shfl_down(s0, off);
        s1 += __shfl_down(s1, off);
        s2 += __shfl_down(s2, off);
    }
    if (lane == 0) {
        h2[(size_t)wave * 3 + 0] = s0;
        h2[(size_t)wave * 3 + 1] = s1;
        h2[(size_t)wave * 3 + 2] = s2;
    }
}

// ---- layer-2 edge pass A: max. thread = edge, blockIdx.y = branch ----
__global__ void k_edge_max2(const int* __restrict__ A1, const int* __restrict__ A2,
                            const int* __restrict__ A3,
                            const float* __restrict__ h2,
                            const float* __restrict__ as1, const float* __restrict__ ad1,
                            const float* __restrict__ as2, const float* __restrict__ ad2,
                            const float* __restrict__ as3, const float* __restrict__ ad3,
                            float* __restrict__ emax, int E, int N) {
    int e = blockIdx.x * blockDim.x + threadIdx.x;
    if (e >= E + N) return;
    int r = blockIdx.y;
    const int* A = (r == 0) ? A1 : (r == 1) ? A2 : A3;
    float a_s = ((r == 0) ? as1 : (r == 1) ? as2 : as3)[0];
    float a_d = ((r == 0) ? ad1 : (r == 1) ? ad2 : ad3)[0];
    int src, dst;
    if (e < E) { src = A[e]; dst = A[E + e]; }
    else       { src = dst = e - E; }
    float v = a_s * h2[(size_t)src * 3 + r] + a_d * h2[(size_t)dst * 3 + r];
    v = (v >= 0.f) ? v : NEG_SLOPE * v;
    atomicMaxF(&emax[(size_t)dst * 3 + r], v);
}

// ---- layer-2 edge pass B ----
__global__ void k_edge_acc2(const int* __restrict__ A1, const int* __restrict__ A2,
                            const int* __restrict__ A3,
                            const float* __restrict__ h2,
                            const float* __restrict__ as1, const float* __restrict__ ad1,
                            const float* __restrict__ as2, const float* __restrict__ ad2,
                            const float* __restrict__ as3, const float* __restrict__ ad3,
                            const float* __restrict__ emax,
                            float* __restrict__ denom, float* __restrict__ acc,
                            int E, int N) {
    int e = blockIdx.x * blockDim.x + threadIdx.x;
    if (e >= E + N) return;
    int r = blockIdx.y;
    const int* A = (r == 0) ? A1 : (r == 1) ? A2 : A3;
    float a_s = ((r == 0) ? as1 : (r == 1) ? as2 : as3)[0];
    float a_d = ((r == 0) ? ad1 : (r == 1) ? ad2 : ad3)[0];
    int src, dst;
    if (e < E) { src = A[e]; dst = A[E + e]; }
    else       { src = dst = e - E; }
    float hs = h2[(size_t)src * 3 + r];
    float v = a_s * hs + a_d * h2[(size_t)dst * 3 + r];
    v = (v >= 0.f) ? v : NEG_SLOPE * v;
    float ex = __expf(v - emax[(size_t)dst * 3 + r]);
    atomicAdd(&denom[(size_t)dst * 3 + r], ex);
    atomicAdd(&acc[(size_t)dst * 3 + r], ex * hs);
}

// ---- final: Y_r = acc/denom + b_r; out = Y @ ln_w + ln_b ----
__global__ void k_final(const float* __restrict__ acc, const float* __restrict__ denom,
                        const float* __restrict__ b1, const float* __restrict__ b2,
                        const float* __restrict__ b3,
                        const float* __restrict__ ln_w, const float* __restrict__ ln_b,
                        float* __restrict__ out, int N) {
    int n = blockIdx.x * blockDim.x + threadIdx.x;
    if (n >= N) return;
    float y0 = acc[(size_t)n * 3 + 0] / (denom[(size_t)n * 3 + 0] + 1e-16f) + b1[0];
    float y1 = acc[(size_t)n * 3 + 1] / (denom[(size_t)n * 3 + 1] + 1e-16f) + b2[0];
    float y2 = acc[(size_t)n * 3 + 2] / (denom[(size_t)n * 3 + 2] + 1e-16f) + b3[0];
    out[n] = y0 * ln_w[0] + y1 * ln_w[1] + y2 * ln_w[2] + ln_b[0];
}

extern "C" void kernel_launch(void* const* d_in, const int* in_sizes, int n_in,
                              void* d_out, int out_size, void* d_ws, size_t ws_size,
                              hipStream_t stream) {
    const float* X  = (const float*)d_in[0];
    const int*   A1 = (const int*)d_in[1];
    const int*   A2 = (const int*)d_in[2];
    const int*   A3 = (const int*)d_in[3];
    // d_in[4] = edge_feature (unused)
    const float* W11 = (const float*)d_in[5];
    const float* as11 = (const float*)d_in[6];
    const float* ad11 = (const float*)d_in[7];
    const float* b11 = (const float*)d_in[8];
    const float* W12 = (const float*)d_in[9];
    const float* as12 = (const float*)d_in[10];
    const float* ad12 = (const float*)d_in[11];
    const float* b12 = (const float*)d_in[12];
    const float* W21 = (const float*)d_in[13];
    const float* as21 = (const float*)d_in[14];
    const float* ad21 = (const float*)d_in[15];
    const float* b21 = (const float*)d_in[16];
    const float* W22 = (const float*)d_in[17];
    const float* as22 = (const float*)d_in[18];
    const float* ad22 = (const float*)d_in[19];
    const float* b22 = (const float*)d_in[20];
    const float* W31 = (const float*)d_in[21];
    const float* as31 = (const float*)d_in[22];
    const float* ad31 = (const float*)d_in[23];
    const float* b31 = (const float*)d_in[24];
    const float* W32 = (const float*)d_in[25];
    const float* as32 = (const float*)d_in[26];
    const float* ad32 = (const float*)d_in[27];
    const float* b32 = (const float*)d_in[28];
    const float* ln_w = (const float*)d_in[29];
    const float* ln_b = (const float*)d_in[30];

    const int N = in_sizes[0] / 64;
    const int E = in_sizes[1] / 2;

    // workspace layout (floats)
    float* w = (float*)d_ws;
    float* h_all  = w; w += (size_t)N * 384;   // layer-1 h; reused as Xc
    float* acc1   = w; w += (size_t)N * 384;
    float* denom1 = w; w += (size_t)N * 24;    // contiguous with acc1 for one memset
    float* s_src1 = w; w += (size_t)N * 24;
    float* s_dst1 = w; w += (size_t)N * 24;
    float* emax1  = w; w += (size_t)N * 24;
    float* h2     = w; w += (size_t)N * 3;
    float* acc2   = w; w += (size_t)N * 3;
    float* denom2 = w; w += (size_t)N * 3;     // contiguous with acc2
    float* emax2  = w; w += (size_t)N * 3;

    const int BLK = 256;

    // zero acc1+denom1 (contiguous), acc2+denom2 (contiguous)
    hipMemsetAsync(acc1, 0, (size_t)N * (384 + 24) * sizeof(float), stream);
    hipMemsetAsync(acc2, 0, (size_t)N * 6 * sizeof(float), stream);
    // emax init to -inf
    {
        int n1 = N * 24, n2 = N * 3;
        k_fill<<<(n1 + BLK - 1) / BLK, BLK, 0, stream>>>(emax1, -INFINITY, n1);
        k_fill<<<(n2 + BLK - 1) / BLK, BLK, 0, stream>>>(emax2, -INFINITY, n2);
    }

    // layer 1
    k_linear1<<<(N + 15) / 16, BLK, 0, stream>>>(X, W11, W21, W31, h_all, N);
    {
        int tot = N * 24;
        k_scores1<<<(tot + BLK - 1) / BLK, BLK, 0, stream>>>(
            h_all, as11, ad11, as21, ad21, as31, ad31, s_src1, s_dst1, N);
    }
    {
        int tot = (E + N) * 8;
        dim3 grid((tot + BLK - 1) / BLK, 3);
        k_edge_max1<<<grid, BLK, 0, stream>>>(A1, A2, A3, s_src1, s_dst1, emax1, E, N);
        k_edge_acc1<<<grid, BLK, 0, stream>>>(A1, A2, A3, s_src1, s_dst1, emax1,
                                              h_all, denom1, acc1, E, N);
    }
    {
        int tot = N * 384;
        k_norm1<<<(tot + BLK - 1) / BLK, BLK, 0, stream>>>(acc1, denom1, b11, b21, b31,
                                                           h_all, N);  // h_all is now Xc
    }

    // layer 2
    {
        int tot = N * 64;  // one wave per node
        k_linear2<<<(tot + BLK - 1) / BLK, BLK, 0, stream>>>(h_all, W12, W22, W32, h2, N);
    }
    {
        int tot = E + N;
        dim3 grid((tot + BLK - 1) / BLK, 3);
        k_edge_max2<<<grid, BLK, 0, stream>>>(A1, A2, A3, h2,
                                              as12, ad12, as22, ad22, as32, ad32,
                                              emax2, E, N);
        k_edge_acc2<<<grid, BLK, 0, stream>>>(A1, A2, A3, h2,
                                              as12, ad12, as22, ad22, as32, ad32,
                                              emax2, denom2, acc2, E, N);
    }
    k_final<<<(N + BLK - 1) / BLK, BLK, 0, stream>>>(acc2, denom2, b12, b22, b32,
                                                     ln_w, ln_b, (float*)d_out, N);
}

// Round 2
// 963.050 us; speedup vs baseline: 20.0211x; 20.0211x over previous
//
#include <hip/hip_runtime.h>
#include <cstdint>
#include <cstddef>

#define NEG_SLOPE 0.2f

__device__ __forceinline__ float lrelu(float v) { return v >= 0.f ? v : NEG_SLOPE * v; }

// ---- CSR build: degree count ----
__global__ void k_deg(const int* __restrict__ A1, const int* __restrict__ A2,
                      const int* __restrict__ A3, int* __restrict__ deg, int E, int N) {
    int e = blockIdx.x * blockDim.x + threadIdx.x;
    if (e >= E) return;
    int r = blockIdx.y;
    const int* A = (r == 0) ? A1 : (r == 1) ? A2 : A3;
    atomicAdd(&deg[(size_t)r * N + A[E + e]], 1);
}

// ---- CSR build: exclusive prefix scan per branch (one block per branch) ----
__global__ void k_scan(const int* __restrict__ deg, int* __restrict__ start, int N) {
    __shared__ int tmp[1024];
    __shared__ int carry;
    const int* d = deg + (size_t)blockIdx.x * N;
    int* s = start + (size_t)blockIdx.x * N;
    if (threadIdx.x == 0) carry = 0;
    __syncthreads();
    for (int base = 0; base < N; base += 1024) {
        int i = base + threadIdx.x;
        int v = (i < N) ? d[i] : 0;
        tmp[threadIdx.x] = v;
        __syncthreads();
        for (int off = 1; off < 1024; off <<= 1) {
            int t = (threadIdx.x >= off) ? tmp[threadIdx.x - off] : 0;
            __syncthreads();
            tmp[threadIdx.x] += t;
            __syncthreads();
        }
        int incl = tmp[threadIdx.x];
        if (i < N) s[i] = carry + incl - v;
        __syncthreads();
        if (threadIdx.x == 1023) carry += incl;
        __syncthreads();
    }
}

// ---- CSR build: scatter src indices into dst buckets ----
__global__ void k_scatter(const int* __restrict__ A1, const int* __restrict__ A2,
                          const int* __restrict__ A3,
                          const int* __restrict__ start, int* __restrict__ cnt,
                          int* __restrict__ csr, int E, int N) {
    int e = blockIdx.x * blockDim.x + threadIdx.x;
    if (e >= E) return;
    int r = blockIdx.y;
    const int* A = (r == 0) ? A1 : (r == 1) ? A2 : A3;
    int src = A[e], dst = A[E + e];
    int pos = start[(size_t)r * N + dst] + atomicAdd(&cnt[(size_t)r * N + dst], 1);
    csr[(size_t)r * E + pos] = src;
}

// ---- layer 1 linear: h_all[n, r*128+col] ----
__global__ void k_linear1(const float* __restrict__ X,
                          const float* __restrict__ W1,
                          const float* __restrict__ W2,
                          const float* __restrict__ W3,
                          float* __restrict__ h_all, int N) {
    __shared__ float Xs[16][64];
    int n0 = blockIdx.x * 16;
    for (int i = threadIdx.x; i < 16 * 64; i += blockDim.x) {
        int nl = i >> 6, k = i & 63;
        int n = n0 + nl;
        Xs[nl][k] = (n < N) ? X[(size_t)n * 64 + k] : 0.f;
    }
    __syncthreads();
    for (int idx = threadIdx.x; idx < 16 * 384; idx += blockDim.x) {
        int nl = idx / 384;
        int j  = idx - nl * 384;
        int n  = n0 + nl;
        if (n >= N) continue;
        int r = j >> 7, col = j & 127;
        const float* W = (r == 0) ? W1 : (r == 1) ? W2 : W3;
        float acc = 0.f;
        #pragma unroll
        for (int k = 0; k < 64; ++k) acc = fmaf(Xs[nl][k], W[k * 128 + col], acc);
        h_all[(size_t)n * 384 + j] = acc;
    }
}

// ---- per-node attention scores ----
__global__ void k_scores1(const float* __restrict__ h_all,
                          const float* __restrict__ as1, const float* __restrict__ ad1,
                          const float* __restrict__ as2, const float* __restrict__ ad2,
                          const float* __restrict__ as3, const float* __restrict__ ad3,
                          float* __restrict__ s_src, float* __restrict__ s_dst, int N) {
    int id = blockIdx.x * blockDim.x + threadIdx.x;
    if (id >= N * 24) return;
    int n = id / 24;
    int rh = id - n * 24;
    int r = rh >> 3, head = rh & 7;
    const float* a_s = (r == 0) ? as1 : (r == 1) ? as2 : as3;
    const float* a_d = (r == 0) ? ad1 : (r == 1) ? ad2 : ad3;
    const float* hp = h_all + (size_t)n * 384 + r * 128 + head * 16;
    const float* ap_s = a_s + head * 16;
    const float* ap_d = a_d + head * 16;
    float ss = 0.f, sd = 0.f;
    #pragma unroll
    for (int c = 0; c < 16; ++c) {
        float hv = hp[c];
        ss = fmaf(hv, ap_s[c], ss);
        sd = fmaf(hv, ap_d[c], sd);
    }
    s_src[id] = ss;
    s_dst[id] = sd;
}

// ---- layer-1 aggregation: one block per (dst, branch), 128 threads = (head, ch) ----
// Fuses: segment max, exp-sum, weighted aggregation, normalize, bias, relu.
__global__ void k_agg1(const float* __restrict__ h_all,
                       const float* __restrict__ s_src, const float* __restrict__ s_dst,
                       const int* __restrict__ deg, const int* __restrict__ start,
                       const int* __restrict__ csr,
                       const float* __restrict__ b1, const float* __restrict__ b2,
                       const float* __restrict__ b3,
                       float* __restrict__ Xc, int E, int N) {
    int n = blockIdx.x;
    int r = blockIdx.y;
    int j = threadIdx.x;          // 0..127 = head*16 + ch
    int h = j >> 4;
    const int* cs = csr + (size_t)r * E;
    int s0 = start[(size_t)r * N + n];
    int d  = deg[(size_t)r * N + n];
    float sd = s_dst[(size_t)n * 24 + r * 8 + h];
    // self loop (always present, src = dst = n)
    float self_v = lrelu(s_src[(size_t)n * 24 + r * 8 + h] + sd);
    float mx = self_v;
    for (int i = 0; i < d; ++i) {
        int src = cs[s0 + i];
        mx = fmaxf(mx, lrelu(s_src[(size_t)src * 24 + r * 8 + h] + sd));
    }
    float ex = __expf(self_v - mx);
    float denom = ex;
    float acc = ex * h_all[(size_t)n * 384 + r * 128 + j];
    for (int i = 0; i < d; ++i) {
        int src = cs[s0 + i];
        float e2 = __expf(lrelu(s_src[(size_t)src * 24 + r * 8 + h] + sd) - mx);
        denom += e2;
        acc = fmaf(e2, h_all[(size_t)src * 384 + r * 128 + j], acc);
    }
    const float* b = (r == 0) ? b1 : (r == 1) ? b2 : b3;
    float out = acc / (denom + 1e-16f) + b[j];
    Xc[(size_t)n * 384 + r * 128 + j] = (out > 0.f) ? out : 0.f;
}

// ---- layer 2 linear: one wave per node, 3 branch dots over 384 ----
__global__ void k_linear2(const float* __restrict__ Xc,
                          const float* __restrict__ W1, const float* __restrict__ W2,
                          const float* __restrict__ W3,
                          float* __restrict__ h2, int N) {
    int gid = blockIdx.x * blockDim.x + threadIdx.x;
    int wave = gid >> 6;
    int lane = gid & 63;
    if (wave >= N) return;
    const float* xp = Xc + (size_t)wave * 384;
    float s0 = 0.f, s1 = 0.f, s2 = 0.f;
    #pragma unroll
    for (int j0 = 0; j0 < 384; j0 += 64) {
        float x = xp[j0 + lane];
        s0 = fmaf(x, W1[j0 + lane], s0);
        s1 = fmaf(x, W2[j0 + lane], s1);
        s2 = fmaf(x, W3[j0 + lane], s2);
    }
    #pragma unroll
    for (int off = 32; off > 0; off >>= 1) {
        s0 += __shfl_down(s0, off);
        s1 += __shfl_down(s1, off);
        s2 += __shfl_down(s2, off);
    }
    if (lane == 0) {
        h2[(size_t)wave * 3 + 0] = s0;
        h2[(size_t)wave * 3 + 1] = s1;
        h2[(size_t)wave * 3 + 2] = s2;
    }
}

// ---- layer-2 aggregation: one thread per (dst, branch) ----
__global__ void k_agg2(const float* __restrict__ h2,
                       const int* __restrict__ deg, const int* __restrict__ start,
                       const int* __restrict__ csr,
                       const float* __restrict__ as1, const float* __restrict__ ad1,
                       const float* __restrict__ as2, const float* __restrict__ ad2,
                       const float* __restrict__ as3, const float* __restrict__ ad3,
                       const float* __restrict__ b1, const float* __restrict__ b2,
                       const float* __restrict__ b3,
                       float* __restrict__ Y, int E, int N) {
    int id = blockIdx.x * blockDim.x + threadIdx.x;
    if (id >= 3 * N) return;
    int r = id / N;
    int n = id - r * N;
    float a_s = ((r == 0) ? as1 : (r == 1) ? as2 : as3)[0];
    float a_d = ((r == 0) ? ad1 : (r == 1) ? ad2 : ad3)[0];
    const int* cs = csr + (size_t)r * E;
    int s0 = start[(size_t)r * N + n];
    int d  = deg[(size_t)r * N + n];
    float hd = h2[(size_t)n * 3 + r];
    float sd = a_d * hd;
    float self_v = lrelu(a_s * hd + sd);
    float mx = self_v;
    for (int i = 0; i < d; ++i) {
        int src = cs[s0 + i];
        mx = fmaxf(mx, lrelu(a_s * h2[(size_t)src * 3 + r] + sd));
    }
    float ex = __expf(self_v - mx);
    float denom = ex;
    float acc = ex * hd;
    for (int i = 0; i < d; ++i) {
        int src = cs[s0 + i];
        float hs = h2[(size_t)src * 3 + r];
        float e2 = __expf(lrelu(a_s * hs + sd) - mx);
        denom += e2;
        acc = fmaf(e2, hs, acc);
    }
    float b = ((r == 0) ? b1 : (r == 1) ? b2 : b3)[0];
    Y[(size_t)n * 3 + r] = acc / (denom + 1e-16f) + b;
}

// ---- final: out = Y @ ln_w + ln_b ----
__global__ void k_final(const float* __restrict__ Y,
                        const float* __restrict__ ln_w, const float* __restrict__ ln_b,
                        float* __restrict__ out, int N) {
    int n = blockIdx.x * blockDim.x + threadIdx.x;
    if (n >= N) return;
    out[n] = Y[(size_t)n * 3 + 0] * ln_w[0] + Y[(size_t)n * 3 + 1] * ln_w[1]
           + Y[(size_t)n * 3 + 2] * ln_w[2] + ln_b[0];
}

extern "C" void kernel_launch(void* const* d_in, const int* in_sizes, int n_in,
                              void* d_out, int out_size, void* d_ws, size_t ws_size,
                              hipStream_t stream) {
    const float* X  = (const float*)d_in[0];
    const int*   A1 = (const int*)d_in[1];
    const int*   A2 = (const int*)d_in[2];
    const int*   A3 = (const int*)d_in[3];
    // d_in[4] = edge_feature (unused)
    const float* W11 = (const float*)d_in[5];
    const float* as11 = (const float*)d_in[6];
    const float* ad11 = (const float*)d_in[7];
    const float* b11 = (const float*)d_in[8];
    const float* W12 = (const float*)d_in[9];
    const float* as12 = (const float*)d_in[10];
    const float* ad12 = (const float*)d_in[11];
    const float* b12 = (const float*)d_in[12];
    const float* W21 = (const float*)d_in[13];
    const float* as21 = (const float*)d_in[14];
    const float* ad21 = (const float*)d_in[15];
    const float* b21 = (const float*)d_in[16];
    const float* W22 = (const float*)d_in[17];
    const float* as22 = (const float*)d_in[18];
    const float* ad22 = (const float*)d_in[19];
    const float* b22 = (const float*)d_in[20];
    const float* W31 = (const float*)d_in[21];
    const float* as31 = (const float*)d_in[22];
    const float* ad31 = (const float*)d_in[23];
    const float* b31 = (const float*)d_in[24];
    const float* W32 = (const float*)d_in[25];
    const float* as32 = (const float*)d_in[26];
    const float* ad32 = (const float*)d_in[27];
    const float* b32 = (const float*)d_in[28];
    const float* ln_w = (const float*)d_in[29];
    const float* ln_b = (const float*)d_in[30];

    const int N = in_sizes[0] / 64;
    const int E = in_sizes[1] / 2;

    // workspace layout
    float* w = (float*)d_ws;
    float* h_all  = w; w += (size_t)N * 384;
    float* Xc     = w; w += (size_t)N * 384;
    float* s_src1 = w; w += (size_t)N * 24;
    float* s_dst1 = w; w += (size_t)N * 24;
    float* h2     = w; w += (size_t)N * 3;
    float* Y      = w; w += (size_t)N * 3;
    int* iw    = (int*)w;
    int* deg   = iw; iw += (size_t)3 * N;
    int* cnt   = iw; iw += (size_t)3 * N;   // contiguous with deg -> one memset
    int* start = iw; iw += (size_t)3 * N;
    int* csr   = iw; iw += (size_t)3 * E;

    const int BLK = 256;

    // ---- CSR build (shared by both layers) ----
    hipMemsetAsync(deg, 0, (size_t)6 * N * sizeof(int), stream);
    {
        dim3 grid((E + BLK - 1) / BLK, 3);
        k_deg<<<grid, BLK, 0, stream>>>(A1, A2, A3, deg, E, N);
        k_scan<<<3, 1024, 0, stream>>>(deg, start, N);
        k_scatter<<<grid, BLK, 0, stream>>>(A1, A2, A3, start, cnt, csr, E, N);
    }

    // ---- layer 1 ----
    k_linear1<<<(N + 15) / 16, BLK, 0, stream>>>(X, W11, W21, W31, h_all, N);
    {
        int tot = N * 24;
        k_scores1<<<(tot + BLK - 1) / BLK, BLK, 0, stream>>>(
            h_all, as11, ad11, as21, ad21, as31, ad31, s_src1, s_dst1, N);
    }
    {
        dim3 grid(N, 3);
        k_agg1<<<grid, 128, 0, stream>>>(h_all, s_src1, s_dst1, deg, start, csr,
                                         b11, b21, b31, Xc, E, N);
    }

    // ---- layer 2 ----
    {
        int tot = N * 64;
        k_linear2<<<(tot + BLK - 1) / BLK, BLK, 0, stream>>>(Xc, W12, W22, W32, h2, N);
    }
    {
        int tot = 3 * N;
        k_agg2<<<(tot + BLK - 1) / BLK, BLK, 0, stream>>>(
            h2, deg, start, csr,
            as12, ad12, as22, ad22, as32, ad32,
            b12, b22, b32, Y, E, N);
    }
    k_final<<<(N + BLK - 1) / BLK, BLK, 0, stream>>>(Y, ln_w, ln_b, (float*)d_out, N);
}

// Round 4
// 792.669 us; speedup vs baseline: 24.3246x; 1.2149x over previous
//
#include <hip/hip_runtime.h>
#include <cstdint>
#include <cstddef>

#define NEG_SLOPE 0.2f

__device__ __forceinline__ float lrelu(float v) { return v >= 0.f ? v : NEG_SLOPE * v; }

// ==================== CSR build ====================
__global__ void k_deg(const int* __restrict__ A1, const int* __restrict__ A2,
                      const int* __restrict__ A3, int* __restrict__ deg, int E, int N) {
    int e = blockIdx.x * blockDim.x + threadIdx.x;
    if (e >= E) return;
    int r = blockIdx.y;
    const int* A = (r == 0) ? A1 : (r == 1) ? A2 : A3;
    atomicAdd(&deg[(size_t)r * N + A[E + e]], 1);
}

// Phase A: block-local exclusive scan of 1024 items (256 thr x 4), block total -> bsum
__global__ void k_scanA(const int* __restrict__ deg, int* __restrict__ start,
                        int* __restrict__ bsum, int total) {
    __shared__ int tmp[256];
    int t = threadIdx.x;
    int base = blockIdx.x * 1024 + t * 4;
    int v[4]; int s = 0;
    #pragma unroll
    for (int k = 0; k < 4; ++k) { v[k] = (base + k < total) ? deg[base + k] : 0; s += v[k]; }
    tmp[t] = s; __syncthreads();
    for (int off = 1; off < 256; off <<= 1) {
        int x = (t >= off) ? tmp[t - off] : 0; __syncthreads();
        tmp[t] += x; __syncthreads();
    }
    int run = tmp[t] - s;
    #pragma unroll
    for (int k = 0; k < 4; ++k) {
        if (base + k < total) start[base + k] = run;
        run += v[k];
    }
    if (t == 255) bsum[blockIdx.x] = tmp[255];
}

// Phase B: one block, exclusive scan of up to 1024 block sums in place
__global__ void k_scanB(int* __restrict__ bsum, int nb) {
    __shared__ int tmp[256];
    int t = threadIdx.x;
    int v[4]; int s = 0;
    #pragma unroll
    for (int k = 0; k < 4; ++k) { int i = t * 4 + k; v[k] = (i < nb) ? bsum[i] : 0; s += v[k]; }
    tmp[t] = s; __syncthreads();
    for (int off = 1; off < 256; off <<= 1) {
        int x = (t >= off) ? tmp[t - off] : 0; __syncthreads();
        tmp[t] += x; __syncthreads();
    }
    int run = tmp[t] - s;
    #pragma unroll
    for (int k = 0; k < 4; ++k) {
        int i = t * 4 + k;
        if (i < nb) { int vv = v[k]; bsum[i] = run; run += vv; }
    }
}

// Phase C: start[g] = local + blockoffset - r*E  (sum of degrees per branch == E)
__global__ void k_scanC(int* __restrict__ start, const int* __restrict__ bsum,
                        int total, int N, int E) {
    int g = blockIdx.x * blockDim.x + threadIdx.x;
    if (g >= total) return;
    int r = g / N;
    start[g] += bsum[g >> 10] - r * E;
}

__global__ void k_scatter(const int* __restrict__ A1, const int* __restrict__ A2,
                          const int* __restrict__ A3,
                          const int* __restrict__ start, int* __restrict__ cnt,
                          int* __restrict__ csr, int E, int N) {
    int e = blockIdx.x * blockDim.x + threadIdx.x;
    if (e >= E) return;
    int r = blockIdx.y;
    const int* A = (r == 0) ? A1 : (r == 1) ? A2 : A3;
    int src = A[e], dst = A[E + e];
    int pos = start[(size_t)r * N + dst] + atomicAdd(&cnt[(size_t)r * N + dst], 1);
    csr[(size_t)r * E + pos] = src;
}

// ==================== layer 1 ====================
// h_all[n, r*128 + col], float4 outputs
__global__ void k_linear1(const float* __restrict__ X,
                          const float* __restrict__ W1,
                          const float* __restrict__ W2,
                          const float* __restrict__ W3,
                          float* __restrict__ h_all, int N) {
    __shared__ float Xs[16][64];
    int n0 = blockIdx.x * 16;
    int t = threadIdx.x;
    {
        int nl = t >> 4, k4 = t & 15;
        int n = n0 + nl;
        float4 xv = make_float4(0.f, 0.f, 0.f, 0.f);
        if (n < N) xv = reinterpret_cast<const float4*>(X + (size_t)n * 64)[k4];
        reinterpret_cast<float4*>(&Xs[nl][0])[k4] = xv;
    }
    __syncthreads();
    for (int g = t; g < 16 * 96; g += 256) {
        int nl = g / 96;
        int cg = g - nl * 96;
        int n = n0 + nl;
        if (n >= N) continue;
        int r = cg >> 5;
        int c4 = cg & 31;
        const float* W = (r == 0) ? W1 : (r == 1) ? W2 : W3;
        const float4* Wv = reinterpret_cast<const float4*>(W) + c4;
        float4 a = make_float4(0.f, 0.f, 0.f, 0.f);
        #pragma unroll
        for (int k = 0; k < 64; ++k) {
            float x = Xs[nl][k];
            float4 wv = Wv[(size_t)k * 32];
            a.x = fmaf(x, wv.x, a.x); a.y = fmaf(x, wv.y, a.y);
            a.z = fmaf(x, wv.z, a.z); a.w = fmaf(x, wv.w, a.w);
        }
        reinterpret_cast<float4*>(h_all + (size_t)n * 384 + r * 128)[c4] = a;
    }
}

__global__ void k_scores1(const float* __restrict__ h_all,
                          const float* __restrict__ as1, const float* __restrict__ ad1,
                          const float* __restrict__ as2, const float* __restrict__ ad2,
                          const float* __restrict__ as3, const float* __restrict__ ad3,
                          float* __restrict__ s_src, float* __restrict__ s_dst, int N) {
    int id = blockIdx.x * blockDim.x + threadIdx.x;
    if (id >= N * 24) return;
    int n = id / 24;
    int rh = id - n * 24;
    int r = rh >> 3, head = rh & 7;
    const float* a_s = (r == 0) ? as1 : (r == 1) ? as2 : as3;
    const float* a_d = (r == 0) ? ad1 : (r == 1) ? ad2 : ad3;
    const float* hp = h_all + (size_t)n * 384 + r * 128 + head * 16;
    const float* ap_s = a_s + head * 16;
    const float* ap_d = a_d + head * 16;
    float ss = 0.f, sd = 0.f;
    #pragma unroll
    for (int c = 0; c < 16; ++c) {
        float hv = hp[c];
        ss = fmaf(hv, ap_s[c], ss);
        sd = fmaf(hv, ap_d[c], sd);
    }
    s_src[id] = ss;
    s_dst[id] = sd;
}

// global max of s_src per (r,h): Mg[24]
__global__ void k_gmax1(const float* __restrict__ s_src, float* __restrict__ Mg, int N) {
    int rh = blockIdx.x;  // 0..23
    float m = -INFINITY;
    for (int n = threadIdx.x; n < N; n += blockDim.x)
        m = fmaxf(m, s_src[(size_t)n * 24 + rh]);
    __shared__ float red[256];
    red[threadIdx.x] = m; __syncthreads();
    for (int off = 128; off > 0; off >>= 1) {
        if (threadIdx.x < off) red[threadIdx.x] = fmaxf(red[threadIdx.x], red[threadIdx.x + off]);
        __syncthreads();
    }
    if (threadIdx.x == 0) Mg[rh] = red[0];
}

// single-pass aggregation: block = (dst n, branch r), 128 threads = head*16+ch
__global__ void k_agg1(const float* __restrict__ h_all,
                       const float* __restrict__ s_src, const float* __restrict__ s_dst,
                       const float* __restrict__ Mg,
                       const int* __restrict__ deg, const int* __restrict__ start,
                       const int* __restrict__ csr,
                       const float* __restrict__ b1, const float* __restrict__ b2,
                       const float* __restrict__ b3,
                       float* __restrict__ Xc, int E, int N) {
    __shared__ int sidx[128];
    __shared__ float sex[128 * 8];
    int n = blockIdx.x;
    int r = blockIdx.y;
    int j = threadIdx.x;          // 0..127
    int h = j >> 4;
    int rh = r * 8 + h;
    int s0 = start[(size_t)r * N + n];
    int d  = deg[(size_t)r * N + n];
    // stabilizer bound (>= every lrelu(ss+sd) for this dst incl. self; lrelu monotone)
    float sd = s_dst[(size_t)n * 24 + rh];
    float bound = lrelu(Mg[rh] + sd);
    // self loop
    float ex0 = __expf(lrelu(s_src[(size_t)n * 24 + rh] + sd) - bound);
    float denom = ex0;
    float acc = ex0 * h_all[(size_t)n * 384 + r * 128 + j];
    // phase-A constants for this thread (p strides by 128 ≡ 0 mod 8 → head = j&7 fixed)
    int hA = j & 7;
    float sdA = s_dst[(size_t)n * 24 + r * 8 + hA];
    float bndA = lrelu(Mg[r * 8 + hA] + sdA);
    const int* cs = csr + (size_t)r * E + s0;
    for (int c0 = 0; c0 < d; c0 += 128) {
        int dc = min(128, d - c0);
        if (j < dc) sidx[j] = cs[c0 + j];
        __syncthreads();
        // phase A: one exp per (neighbor, head)
        for (int p = j; p < dc * 8; p += 128) {
            int i = p >> 3;
            float ssv = s_src[(size_t)sidx[i] * 24 + r * 8 + hA];
            sex[p] = __expf(lrelu(ssv + sdA) - bndA);
        }
        __syncthreads();
        // phase B: gather + accumulate
        for (int i = 0; i < dc; ++i) {
            float ex = sex[i * 8 + h];
            int src = sidx[i];
            denom += ex;
            acc = fmaf(ex, h_all[(size_t)src * 384 + r * 128 + j], acc);
        }
        __syncthreads();
    }
    const float* b = (r == 0) ? b1 : (r == 1) ? b2 : b3;
    float out = acc / (denom + 1e-16f) + b[j];
    Xc[(size_t)n * 384 + r * 128 + j] = (out > 0.f) ? out : 0.f;
}

// ==================== layer 2 ====================
__global__ void k_linear2(const float* __restrict__ Xc,
                          const float* __restrict__ W1, const float* __restrict__ W2,
                          const float* __restrict__ W3,
                          float* __restrict__ h2, int N) {
    int gid = blockIdx.x * blockDim.x + threadIdx.x;
    int wave = gid >> 6;
    int lane = gid & 63;
    if (wave >= N) return;
    const float* xp = Xc + (size_t)wave * 384;
    float s0 = 0.f, s1 = 0.f, s2 = 0.f;
    #pragma unroll
    for (int j0 = 0; j0 < 384; j0 += 64) {
        float x = xp[j0 + lane];
        s0 = fmaf(x, W1[j0 + lane], s0);
        s1 = fmaf(x, W2[j0 + lane], s1);
        s2 = fmaf(x, W3[j0 + lane], s2);
    }
    #pragma unroll
    for (int off = 32; off > 0; off >>= 1) {
        s0 += __shfl_down(s0, off);
        s1 += __shfl_down(s1, off);
        s2 += __shfl_down(s2, off);
    }
    if (lane == 0) {
        h2[(size_t)wave * 3 + 0] = s0;
        h2[(size_t)wave * 3 + 1] = s1;
        h2[(size_t)wave * 3 + 2] = s2;
    }
}

// per-branch max/min of h2: M2[0..2]=max, M2[3..5]=min
__global__ void k_gmax2(const float* __restrict__ h2, float* __restrict__ M2, int N) {
    int r = blockIdx.x;
    float mx = -INFINITY, mn = INFINITY;
    for (int n = threadIdx.x; n < N; n += blockDim.x) {
        float v = h2[(size_t)n * 3 + r];
        mx = fmaxf(mx, v); mn = fminf(mn, v);
    }
    __shared__ float rmx[256], rmn[256];
    rmx[threadIdx.x] = mx; rmn[threadIdx.x] = mn; __syncthreads();
    for (int off = 128; off > 0; off >>= 1) {
        if (threadIdx.x < off) {
            rmx[threadIdx.x] = fmaxf(rmx[threadIdx.x], rmx[threadIdx.x + off]);
            rmn[threadIdx.x] = fminf(rmn[threadIdx.x], rmn[threadIdx.x + off]);
        }
        __syncthreads();
    }
    if (threadIdx.x == 0) { M2[r] = rmx[0]; M2[3 + r] = rmn[0]; }
}

// layer-2 aggregation + final projection fused: one thread per node
__global__ void k_agg2f(const float* __restrict__ h2,
                        const int* __restrict__ deg, const int* __restrict__ start,
                        const int* __restrict__ csr,
                        const float* __restrict__ as1, const float* __restrict__ ad1,
                        const float* __restrict__ as2, const float* __restrict__ ad2,
                        const float* __restrict__ as3, const float* __restrict__ ad3,
                        const float* __restrict__ b1, const float* __restrict__ b2,
                        const float* __restrict__ b3,
                        const float* __restrict__ M2,
                        const float* __restrict__ ln_w, const float* __restrict__ ln_b,
                        float* __restrict__ out, int E, int N) {
    int n = blockIdx.x * blockDim.x + threadIdx.x;
    if (n >= N) return;
    float y[3];
    #pragma unroll
    for (int r = 0; r < 3; ++r) {
        float a_s = ((r == 0) ? as1 : (r == 1) ? as2 : as3)[0];
        float a_d = ((r == 0) ? ad1 : (r == 1) ? ad2 : ad3)[0];
        int s0 = start[(size_t)r * N + n];
        int d  = deg[(size_t)r * N + n];
        float hd = h2[(size_t)n * 3 + r];
        float sd = a_d * hd;
        float bound = lrelu(fmaxf(a_s * M2[r], a_s * M2[3 + r]) + sd);
        float ev = __expf(lrelu(a_s * hd + sd) - bound);
        float denom = ev;
        float acc = ev * hd;
        const int* cs = csr + (size_t)r * E + s0;
        for (int i = 0; i < d; ++i) {
            float hs = h2[(size_t)cs[i] * 3 + r];
            float e2 = __expf(lrelu(a_s * hs + sd) - bound);
            denom += e2;
            acc = fmaf(e2, hs, acc);
        }
        float b = ((r == 0) ? b1 : (r == 1) ? b2 : b3)[0];
        y[r] = acc / (denom + 1e-16f) + b;
    }
    out[n] = y[0] * ln_w[0] + y[1] * ln_w[1] + y[2] * ln_w[2] + ln_b[0];
}

extern "C" void kernel_launch(void* const* d_in, const int* in_sizes, int n_in,
                              void* d_out, int out_size, void* d_ws, size_t ws_size,
                              hipStream_t stream) {
    const float* X  = (const float*)d_in[0];
    const int*   A1 = (const int*)d_in[1];
    const int*   A2 = (const int*)d_in[2];
    const int*   A3 = (const int*)d_in[3];
    // d_in[4] = edge_feature (unused)
    const float* W11 = (const float*)d_in[5];
    const float* as11 = (const float*)d_in[6];
    const float* ad11 = (const float*)d_in[7];
    const float* b11 = (const float*)d_in[8];
    const float* W12 = (const float*)d_in[9];
    const float* as12 = (const float*)d_in[10];
    const float* ad12 = (const float*)d_in[11];
    const float* b12 = (const float*)d_in[12];
    const float* W21 = (const float*)d_in[13];
    const float* as21 = (const float*)d_in[14];
    const float* ad21 = (const float*)d_in[15];
    const float* b21 = (const float*)d_in[16];
    const float* W22 = (const float*)d_in[17];
    const float* as22 = (const float*)d_in[18];
    const float* ad22 = (const float*)d_in[19];
    const float* b22 = (const float*)d_in[20];
    const float* W31 = (const float*)d_in[21];
    const float* as31 = (const float*)d_in[22];
    const float* ad31 = (const float*)d_in[23];
    const float* b31 = (const float*)d_in[24];
    const float* W32 = (const float*)d_in[25];
    const float* as32 = (const float*)d_in[26];
    const float* ad32 = (const float*)d_in[27];
    const float* b32 = (const float*)d_in[28];
    const float* ln_w = (const float*)d_in[29];
    const float* ln_b = (const float*)d_in[30];

    const int N = in_sizes[0] / 64;
    const int E = in_sizes[1] / 2;
    const int total = 3 * N;
    const int nbA = (total + 1023) / 1024;

    // workspace layout
    float* w = (float*)d_ws;
    float* h_all  = w; w += (size_t)N * 384;
    float* Xc     = w; w += (size_t)N * 384;
    float* s_src1 = w; w += (size_t)N * 24;
    float* s_dst1 = w; w += (size_t)N * 24;
    float* h2     = w; w += (size_t)N * 3;
    float* Mg1    = w; w += 32;
    float* M2     = w; w += 8;
    int* iw    = (int*)w;
    int* deg   = iw; iw += (size_t)3 * N;
    int* cnt   = iw; iw += (size_t)3 * N;   // contiguous with deg -> one memset
    int* start = iw; iw += (size_t)3 * N;
    int* bsum  = iw; iw += 1024;
    int* csr   = iw; iw += (size_t)3 * E;

    const int BLK = 256;

    // ---- CSR build (shared by both layers) ----
    hipMemsetAsync(deg, 0, (size_t)6 * N * sizeof(int), stream);
    {
        dim3 grid((E + BLK - 1) / BLK, 3);
        k_deg<<<grid, BLK, 0, stream>>>(A1, A2, A3, deg, E, N);
        k_scanA<<<nbA, 256, 0, stream>>>(deg, start, bsum, total);
        k_scanB<<<1, 256, 0, stream>>>(bsum, nbA);
        k_scanC<<<(total + BLK - 1) / BLK, BLK, 0, stream>>>(start, bsum, total, N, E);
        k_scatter<<<grid, BLK, 0, stream>>>(A1, A2, A3, start, cnt, csr, E, N);
    }

    // ---- layer 1 ----
    k_linear1<<<(N + 15) / 16, BLK, 0, stream>>>(X, W11, W21, W31, h_all, N);
    {
        int tot = N * 24;
        k_scores1<<<(tot + BLK - 1) / BLK, BLK, 0, stream>>>(
            h_all, as11, ad11, as21, ad21, as31, ad31, s_src1, s_dst1, N);
    }
    k_gmax1<<<24, 256, 0, stream>>>(s_src1, Mg1, N);
    {
        dim3 grid(N, 3);
        k_agg1<<<grid, 128, 0, stream>>>(h_all, s_src1, s_dst1, Mg1, deg, start, csr,
                                         b11, b21, b31, Xc, E, N);
    }

    // ---- layer 2 ----
    {
        int tot = N * 64;
        k_linear2<<<(tot + BLK - 1) / BLK, BLK, 0, stream>>>(Xc, W12, W22, W32, h2, N);
    }
    k_gmax2<<<3, 256, 0, stream>>>(h2, M2, N);
    k_agg2f<<<(N + BLK - 1) / BLK, BLK, 0, stream>>>(
        h2, deg, start, csr,
        as12, ad12, as22, ad22, as32, ad32,
        b12, b22, b32, M2, ln_w, ln_b, (float*)d_out, E, N);
}

// Round 5
// 746.180 us; speedup vs baseline: 25.8400x; 1.0623x over previous
//
#include <hip/hip_runtime.h>
#include <cstdint>
#include <cstddef>

#define NEG_SLOPE 0.2f

__device__ __forceinline__ float lrelu(float v) { return v >= 0.f ? v : NEG_SLOPE * v; }

__device__ __forceinline__ void atomicMaxF(float* addr, float val) {
    if (val >= 0.0f) atomicMax((int*)addr, __float_as_int(val));
    else             atomicMin((unsigned int*)addr, __float_as_uint(val));
}
__device__ __forceinline__ void atomicMinF(float* addr, float val) {
    if (val >= 0.0f) atomicMin((int*)addr, __float_as_int(val));
    else             atomicMax((unsigned int*)addr, __float_as_uint(val));
}

// ==================== CSR build ====================
__global__ void k_deg(const int* __restrict__ A1, const int* __restrict__ A2,
                      const int* __restrict__ A3, int* __restrict__ deg, int E, int N) {
    int e = blockIdx.x * blockDim.x + threadIdx.x;
    if (e >= E) return;
    int r = blockIdx.y;
    const int* A = (r == 0) ? A1 : (r == 1) ? A2 : A3;
    atomicAdd(&deg[(size_t)r * N + A[E + e]], 1);
}

__global__ void k_scanA(const int* __restrict__ deg, int* __restrict__ start,
                        int* __restrict__ bsum, int total) {
    __shared__ int tmp[256];
    int t = threadIdx.x;
    int base = blockIdx.x * 1024 + t * 4;
    int v[4]; int s = 0;
    #pragma unroll
    for (int k = 0; k < 4; ++k) { v[k] = (base + k < total) ? deg[base + k] : 0; s += v[k]; }
    tmp[t] = s; __syncthreads();
    for (int off = 1; off < 256; off <<= 1) {
        int x = (t >= off) ? tmp[t - off] : 0; __syncthreads();
        tmp[t] += x; __syncthreads();
    }
    int run = tmp[t] - s;
    #pragma unroll
    for (int k = 0; k < 4; ++k) {
        if (base + k < total) start[base + k] = run;
        run += v[k];
    }
    if (t == 255) bsum[blockIdx.x] = tmp[255];
}

// one block; also re-initializes Mg1/M2 (runs before linear kernels in-stream)
__global__ void k_scanB(int* __restrict__ bsum, int nb,
                        float* __restrict__ Mg, float* __restrict__ M2) {
    __shared__ int tmp[256];
    int t = threadIdx.x;
    if (t < 24) Mg[t] = -INFINITY;
    else if (t < 27) M2[t - 24] = -INFINITY;   // M2[0..2] = branch max
    else if (t < 30) M2[t - 24] = INFINITY;    // M2[3..5] = branch min
    int v[4]; int s = 0;
    #pragma unroll
    for (int k = 0; k < 4; ++k) { int i = t * 4 + k; v[k] = (i < nb) ? bsum[i] : 0; s += v[k]; }
    tmp[t] = s; __syncthreads();
    for (int off = 1; off < 256; off <<= 1) {
        int x = (t >= off) ? tmp[t - off] : 0; __syncthreads();
        tmp[t] += x; __syncthreads();
    }
    int run = tmp[t] - s;
    #pragma unroll
    for (int k = 0; k < 4; ++k) {
        int i = t * 4 + k;
        if (i < nb) { int vv = v[k]; bsum[i] = run; run += vv; }
    }
}

__global__ void k_scanC(int* __restrict__ start, const int* __restrict__ bsum,
                        int total, int N, int E) {
    int g = blockIdx.x * blockDim.x + threadIdx.x;
    if (g >= total) return;
    int r = g / N;
    start[g] += bsum[g >> 10] - r * E;
}

__global__ void k_scatter(const int* __restrict__ A1, const int* __restrict__ A2,
                          const int* __restrict__ A3,
                          const int* __restrict__ start, int* __restrict__ cnt,
                          int* __restrict__ csr, int E, int N) {
    int e = blockIdx.x * blockDim.x + threadIdx.x;
    if (e >= E) return;
    int r = blockIdx.y;
    const int* A = (r == 0) ? A1 : (r == 1) ? A2 : A3;
    int src = A[e], dst = A[E + e];
    int pos = start[(size_t)r * N + dst] + atomicAdd(&cnt[(size_t)r * N + dst], 1);
    csr[(size_t)r * E + pos] = src;
}

// ==================== layer 1: linear + scores + global-max fused ====================
__global__ void k_linear1(const float* __restrict__ X,
                          const float* __restrict__ W1, const float* __restrict__ W2,
                          const float* __restrict__ W3,
                          const float* __restrict__ as1, const float* __restrict__ ad1,
                          const float* __restrict__ as2, const float* __restrict__ ad2,
                          const float* __restrict__ as3, const float* __restrict__ ad3,
                          float* __restrict__ h_all,
                          float* __restrict__ s_src, float* __restrict__ s_dst,
                          float* __restrict__ Mg, int N) {
    __shared__ float Xs[16][64];
    __shared__ float MgLoc[24];
    int t = threadIdx.x;
    if (t < 24) MgLoc[t] = -INFINITY;
    int n0 = blockIdx.x * 16;
    {
        int nl = t >> 4, k4 = t & 15;
        int n = n0 + nl;
        float4 xv = make_float4(0.f, 0.f, 0.f, 0.f);
        if (n < N) xv = reinterpret_cast<const float4*>(X + (size_t)n * 64)[k4];
        reinterpret_cast<float4*>(&Xs[nl][0])[k4] = xv;
    }
    __syncthreads();
    for (int g = t; g < 16 * 96; g += 256) {
        int nl = g / 96;
        int cg = g - nl * 96;
        int n = n0 + nl;
        int r = cg >> 5;
        int c4 = cg & 31;
        int head = c4 >> 2;
        int q = c4 & 3;
        float4 a = make_float4(0.f, 0.f, 0.f, 0.f);
        if (n < N) {
            const float* W = (r == 0) ? W1 : (r == 1) ? W2 : W3;
            const float4* Wv = reinterpret_cast<const float4*>(W) + c4;
            #pragma unroll
            for (int k = 0; k < 64; ++k) {
                float x = Xs[nl][k];
                float4 wv = Wv[(size_t)k * 32];
                a.x = fmaf(x, wv.x, a.x); a.y = fmaf(x, wv.y, a.y);
                a.z = fmaf(x, wv.z, a.z); a.w = fmaf(x, wv.w, a.w);
            }
            reinterpret_cast<float4*>(h_all + (size_t)n * 384 + r * 128)[c4] = a;
        }
        // fused attention scores: quad-reduce over the 4 threads of this head
        const float* As = ((r == 0) ? as1 : (r == 1) ? as2 : as3) + head * 16 + q * 4;
        const float* Ad = ((r == 0) ? ad1 : (r == 1) ? ad2 : ad3) + head * 16 + q * 4;
        float ss = a.x * As[0] + a.y * As[1] + a.z * As[2] + a.w * As[3];
        float sd = a.x * Ad[0] + a.y * Ad[1] + a.z * Ad[2] + a.w * Ad[3];
        ss += __shfl_xor(ss, 1); ss += __shfl_xor(ss, 2);
        sd += __shfl_xor(sd, 1); sd += __shfl_xor(sd, 2);
        if (q == 0 && n < N) {
            int rh = r * 8 + head;
            s_src[(size_t)n * 24 + rh] = ss;
            s_dst[(size_t)n * 24 + rh] = sd;
            atomicMaxF(&MgLoc[rh], ss);
        }
    }
    __syncthreads();
    if (t < 24) atomicMaxF(&Mg[t], MgLoc[t]);
}

// single-pass aggregation: block = (dst n, branch r), 128 threads = head*16+ch
__global__ void k_agg1(const float* __restrict__ h_all,
                       const float* __restrict__ s_src, const float* __restrict__ s_dst,
                       const float* __restrict__ Mg,
                       const int* __restrict__ deg, const int* __restrict__ start,
                       const int* __restrict__ csr,
                       const float* __restrict__ b1, const float* __restrict__ b2,
                       const float* __restrict__ b3,
                       float* __restrict__ Xc, int E, int N) {
    __shared__ int sidx[128];
    __shared__ float sex[128 * 8];
    int n = blockIdx.x;
    int r = blockIdx.y;
    int j = threadIdx.x;
    int h = j >> 4;
    int rh = r * 8 + h;
    int s0 = start[(size_t)r * N + n];
    int d  = deg[(size_t)r * N + n];
    float sd = s_dst[(size_t)n * 24 + rh];
    float bound = lrelu(Mg[rh] + sd);
    float ex0 = __expf(lrelu(s_src[(size_t)n * 24 + rh] + sd) - bound);
    float denom = ex0;
    float acc = ex0 * h_all[(size_t)n * 384 + r * 128 + j];
    int hA = j & 7;
    float sdA = s_dst[(size_t)n * 24 + r * 8 + hA];
    float bndA = lrelu(Mg[r * 8 + hA] + sdA);
    const int* cs = csr + (size_t)r * E + s0;
    for (int c0 = 0; c0 < d; c0 += 128) {
        int dc = min(128, d - c0);
        if (j < dc) sidx[j] = cs[c0 + j];
        __syncthreads();
        for (int p = j; p < dc * 8; p += 128) {
            int i = p >> 3;
            float ssv = s_src[(size_t)sidx[i] * 24 + r * 8 + hA];
            sex[p] = __expf(lrelu(ssv + sdA) - bndA);
        }
        __syncthreads();
        int i = 0;
        for (; i + 1 < dc; i += 2) {
            int sA = sidx[i], sB = sidx[i + 1];
            float exA = sex[i * 8 + h], exB = sex[i * 8 + 8 + h];
            float hva = h_all[(size_t)sA * 384 + r * 128 + j];
            float hvb = h_all[(size_t)sB * 384 + r * 128 + j];
            denom += exA + exB;
            acc = fmaf(exA, hva, acc);
            acc = fmaf(exB, hvb, acc);
        }
        if (i < dc) {
            int sA = sidx[i];
            float exA = sex[i * 8 + h];
            denom += exA;
            acc = fmaf(exA, h_all[(size_t)sA * 384 + r * 128 + j], acc);
        }
        __syncthreads();
    }
    const float* b = (r == 0) ? b1 : (r == 1) ? b2 : b3;
    float out = acc / (denom + 1e-16f) + b[j];
    Xc[(size_t)n * 384 + r * 128 + j] = (out > 0.f) ? out : 0.f;
}

// ==================== layer 2: linear + branch min/max fused ====================
// blockDim 1024 = 16 nodes (one wave each)
__global__ void k_linear2(const float* __restrict__ Xc,
                          const float* __restrict__ W1, const float* __restrict__ W2,
                          const float* __restrict__ W3,
                          float* __restrict__ h2, float* __restrict__ M2, int N) {
    __shared__ float redmx[16][3], redmn[16][3];
    int gid = blockIdx.x * 1024 + threadIdx.x;
    int node = gid >> 6;
    int lane = gid & 63;
    int wv = threadIdx.x >> 6;
    float s0 = 0.f, s1 = 0.f, s2 = 0.f;
    if (node < N) {
        const float* xp = Xc + (size_t)node * 384;
        #pragma unroll
        for (int j0 = 0; j0 < 384; j0 += 64) {
            float x = xp[j0 + lane];
            s0 = fmaf(x, W1[j0 + lane], s0);
            s1 = fmaf(x, W2[j0 + lane], s1);
            s2 = fmaf(x, W3[j0 + lane], s2);
        }
    }
    #pragma unroll
    for (int off = 32; off > 0; off >>= 1) {
        s0 += __shfl_down(s0, off);
        s1 += __shfl_down(s1, off);
        s2 += __shfl_down(s2, off);
    }
    if (lane == 0) {
        if (node < N) {
            h2[(size_t)node * 3 + 0] = s0;
            h2[(size_t)node * 3 + 1] = s1;
            h2[(size_t)node * 3 + 2] = s2;
            redmx[wv][0] = s0; redmx[wv][1] = s1; redmx[wv][2] = s2;
            redmn[wv][0] = s0; redmn[wv][1] = s1; redmn[wv][2] = s2;
        } else {
            redmx[wv][0] = redmx[wv][1] = redmx[wv][2] = -INFINITY;
            redmn[wv][0] = redmn[wv][1] = redmn[wv][2] = INFINITY;
        }
    }
    __syncthreads();
    if (threadIdx.x < 3) {
        float m = -INFINITY;
        for (int w2 = 0; w2 < 16; ++w2) m = fmaxf(m, redmx[w2][threadIdx.x]);
        atomicMaxF(&M2[threadIdx.x], m);
    } else if (threadIdx.x < 6) {
        int rr = threadIdx.x - 3;
        float m = INFINITY;
        for (int w2 = 0; w2 < 16; ++w2) m = fminf(m, redmn[w2][rr]);
        atomicMinF(&M2[3 + rr], m);
    }
}

// layer-2 aggregation + final projection: one thread per (node, branch), blockDim 192
__global__ void k_agg2f(const float* __restrict__ h2,
                        const int* __restrict__ deg, const int* __restrict__ start,
                        const int* __restrict__ csr,
                        const float* __restrict__ as1, const float* __restrict__ ad1,
                        const float* __restrict__ as2, const float* __restrict__ ad2,
                        const float* __restrict__ as3, const float* __restrict__ ad3,
                        const float* __restrict__ b1, const float* __restrict__ b2,
                        const float* __restrict__ b3,
                        const float* __restrict__ M2,
                        const float* __restrict__ ln_w, const float* __restrict__ ln_b,
                        float* __restrict__ out, int E, int N) {
    __shared__ float ys[192];
    int id = blockIdx.x * 192 + threadIdx.x;
    bool valid = id < 3 * N;
    int n = id / 3;
    int r = id - 3 * n;
    float y = 0.f;
    if (valid) {
        float a_s = ((r == 0) ? as1 : (r == 1) ? as2 : as3)[0];
        float a_d = ((r == 0) ? ad1 : (r == 1) ? ad2 : ad3)[0];
        int s0 = start[(size_t)r * N + n];
        int d  = deg[(size_t)r * N + n];
        float hd = h2[id];
        float sd = a_d * hd;
        float bound = lrelu(fmaxf(a_s * M2[r], a_s * M2[3 + r]) + sd);
        float ev = __expf(lrelu(fmaf(a_s, hd, sd)) - bound);
        float denom = ev;
        float acc = ev * hd;
        const int* cs = csr + (size_t)r * E + s0;
        int i = 0;
        for (; i + 1 < d; i += 2) {
            int sA = cs[i], sB = cs[i + 1];
            float hva = h2[(size_t)sA * 3 + r];
            float hvb = h2[(size_t)sB * 3 + r];
            float eA = __expf(lrelu(fmaf(a_s, hva, sd)) - bound);
            float eB = __expf(lrelu(fmaf(a_s, hvb, sd)) - bound);
            denom += eA + eB;
            acc = fmaf(eA, hva, acc);
            acc = fmaf(eB, hvb, acc);
        }
        if (i < d) {
            float hva = h2[(size_t)cs[i] * 3 + r];
            float eA = __expf(lrelu(fmaf(a_s, hva, sd)) - bound);
            denom += eA;
            acc = fmaf(eA, hva, acc);
        }
        float b = ((r == 0) ? b1 : (r == 1) ? b2 : b3)[0];
        y = (acc / (denom + 1e-16f) + b) * ln_w[r];
    }
    ys[threadIdx.x] = y;
    __syncthreads();
    if (valid && r == 0)
        out[n] = ys[threadIdx.x] + ys[threadIdx.x + 1] + ys[threadIdx.x + 2] + ln_b[0];
}

extern "C" void kernel_launch(void* const* d_in, const int* in_sizes, int n_in,
                              void* d_out, int out_size, void* d_ws, size_t ws_size,
                              hipStream_t stream) {
    const float* X  = (const float*)d_in[0];
    const int*   A1 = (const int*)d_in[1];
    const int*   A2 = (const int*)d_in[2];
    const int*   A3 = (const int*)d_in[3];
    const float* W11 = (const float*)d_in[5];
    const float* as11 = (const float*)d_in[6];
    const float* ad11 = (const float*)d_in[7];
    const float* b11 = (const float*)d_in[8];
    const float* W12 = (const float*)d_in[9];
    const float* as12 = (const float*)d_in[10];
    const float* ad12 = (const float*)d_in[11];
    const float* b12 = (const float*)d_in[12];
    const float* W21 = (const float*)d_in[13];
    const float* as21 = (const float*)d_in[14];
    const float* ad21 = (const float*)d_in[15];
    const float* b21 = (const float*)d_in[16];
    const float* W22 = (const float*)d_in[17];
    const float* as22 = (const float*)d_in[18];
    const float* ad22 = (const float*)d_in[19];
    const float* b22 = (const float*)d_in[20];
    const float* W31 = (const float*)d_in[21];
    const float* as31 = (const float*)d_in[22];
    const float* ad31 = (const float*)d_in[23];
    const float* b31 = (const float*)d_in[24];
    const float* W32 = (const float*)d_in[25];
    const float* as32 = (const float*)d_in[26];
    const float* ad32 = (const float*)d_in[27];
    const float* b32 = (const float*)d_in[28];
    const float* ln_w = (const float*)d_in[29];
    const float* ln_b = (const float*)d_in[30];

    const int N = in_sizes[0] / 64;
    const int E = in_sizes[1] / 2;
    const int total = 3 * N;
    const int nbA = (total + 1023) / 1024;

    // workspace layout
    float* w = (float*)d_ws;
    float* h_all  = w; w += (size_t)N * 384;
    float* Xc     = w; w += (size_t)N * 384;
    float* s_src1 = w; w += (size_t)N * 24;
    float* s_dst1 = w; w += (size_t)N * 24;
    float* h2     = w; w += (size_t)N * 3;
    float* Mg1    = w; w += 32;
    float* M2     = w; w += 8;
    int* iw    = (int*)w;
    int* deg   = iw; iw += (size_t)3 * N;
    int* cnt   = iw; iw += (size_t)3 * N;   // contiguous with deg -> one memset
    int* start = iw; iw += (size_t)3 * N;
    int* bsum  = iw; iw += 1024;
    int* csr   = iw; iw += (size_t)3 * E;

    const int BLK = 256;

    // ---- CSR build (shared by both layers) ----
    hipMemsetAsync(deg, 0, (size_t)6 * N * sizeof(int), stream);
    {
        dim3 grid((E + BLK - 1) / BLK, 3);
        k_deg<<<grid, BLK, 0, stream>>>(A1, A2, A3, deg, E, N);
        k_scanA<<<nbA, 256, 0, stream>>>(deg, start, bsum, total);
        k_scanB<<<1, 256, 0, stream>>>(bsum, nbA, Mg1, M2);
        k_scanC<<<(total + BLK - 1) / BLK, BLK, 0, stream>>>(start, bsum, total, N, E);
        k_scatter<<<grid, BLK, 0, stream>>>(A1, A2, A3, start, cnt, csr, E, N);
    }

    // ---- layer 1 ----
    k_linear1<<<(N + 15) / 16, BLK, 0, stream>>>(
        X, W11, W21, W31, as11, ad11, as21, ad21, as31, ad31,
        h_all, s_src1, s_dst1, Mg1, N);
    {
        dim3 grid(N, 3);
        k_agg1<<<grid, 128, 0, stream>>>(h_all, s_src1, s_dst1, Mg1, deg, start, csr,
                                         b11, b21, b31, Xc, E, N);
    }

    // ---- layer 2 ----
    k_linear2<<<(N + 15) / 16, 1024, 0, stream>>>(Xc, W12, W22, W32, h2, M2, N);
    {
        int nb = (total + 191) / 192;
        k_agg2f<<<nb, 192, 0, stream>>>(
            h2, deg, start, csr,
            as12, ad12, as22, ad22, as32, ad32,
            b12, b22, b32, M2, ln_w, ln_b, (float*)d_out, E, N);
    }
}

// Round 6
// 688.435 us; speedup vs baseline: 28.0074x; 1.0839x over previous
//
#include <hip/hip_runtime.h>
#include <cstdint>
#include <cstddef>

#define NEG_SLOPE 0.2f

__device__ __forceinline__ float lrelu(float v) { return v >= 0.f ? v : NEG_SLOPE * v; }

__device__ __forceinline__ void atomicMaxF(float* addr, float val) {
    if (val >= 0.0f) atomicMax((int*)addr, __float_as_int(val));
    else             atomicMin((unsigned int*)addr, __float_as_uint(val));
}
__device__ __forceinline__ void atomicMinF(float* addr, float val) {
    if (val >= 0.0f) atomicMin((int*)addr, __float_as_int(val));
    else             atomicMax((unsigned int*)addr, __float_as_uint(val));
}

// bf16 pack/unpack (round-to-nearest-even)
__device__ __forceinline__ unsigned short f2bf(float x) {
    union { float f; uint32_t u; } v; v.f = x;
    uint32_t r = v.u + 0x7FFFu + ((v.u >> 16) & 1u);
    return (unsigned short)(r >> 16);
}
__device__ __forceinline__ float bf2f(unsigned short h) {
    union { uint32_t u; float f; } v; v.u = (uint32_t)h << 16;
    return v.f;
}

// ==================== CSR build ====================
__global__ void k_deg(const int* __restrict__ A1, const int* __restrict__ A2,
                      const int* __restrict__ A3, int* __restrict__ deg, int E, int N) {
    int e = blockIdx.x * blockDim.x + threadIdx.x;
    if (e >= E) return;
    int r = blockIdx.y;
    const int* A = (r == 0) ? A1 : (r == 1) ? A2 : A3;
    atomicAdd(&deg[(size_t)r * N + A[E + e]], 1);
}

__global__ void k_scanA(const int* __restrict__ deg, int* __restrict__ start,
                        int* __restrict__ bsum, int total) {
    __shared__ int tmp[256];
    int t = threadIdx.x;
    int base = blockIdx.x * 1024 + t * 4;
    int v[4]; int s = 0;
    #pragma unroll
    for (int k = 0; k < 4; ++k) { v[k] = (base + k < total) ? deg[base + k] : 0; s += v[k]; }
    tmp[t] = s; __syncthreads();
    for (int off = 1; off < 256; off <<= 1) {
        int x = (t >= off) ? tmp[t - off] : 0; __syncthreads();
        tmp[t] += x; __syncthreads();
    }
    int run = tmp[t] - s;
    #pragma unroll
    for (int k = 0; k < 4; ++k) {
        if (base + k < total) start[base + k] = run;
        run += v[k];
    }
    if (t == 255) bsum[blockIdx.x] = tmp[255];
}

// one block; also re-initializes Mg1/M2 (runs before linear kernels in-stream)
__global__ void k_scanB(int* __restrict__ bsum, int nb,
                        float* __restrict__ Mg, float* __restrict__ M2) {
    __shared__ int tmp[256];
    int t = threadIdx.x;
    if (t < 24) Mg[t] = -INFINITY;
    else if (t < 27) M2[t - 24] = -INFINITY;   // M2[0..2] = branch max
    else if (t < 30) M2[t - 24] = INFINITY;    // M2[3..5] = branch min
    int v[4]; int s = 0;
    #pragma unroll
    for (int k = 0; k < 4; ++k) { int i = t * 4 + k; v[k] = (i < nb) ? bsum[i] : 0; s += v[k]; }
    tmp[t] = s; __syncthreads();
    for (int off = 1; off < 256; off <<= 1) {
        int x = (t >= off) ? tmp[t - off] : 0; __syncthreads();
        tmp[t] += x; __syncthreads();
    }
    int run = tmp[t] - s;
    #pragma unroll
    for (int k = 0; k < 4; ++k) {
        int i = t * 4 + k;
        if (i < nb) { int vv = v[k]; bsum[i] = run; run += vv; }
    }
}

__global__ void k_scanC(int* __restrict__ start, const int* __restrict__ bsum,
                        int total, int N, int E) {
    int g = blockIdx.x * blockDim.x + threadIdx.x;
    if (g >= total) return;
    int r = g / N;
    start[g] += bsum[g >> 10] - r * E;
}

__global__ void k_scatter(const int* __restrict__ A1, const int* __restrict__ A2,
                          const int* __restrict__ A3,
                          const int* __restrict__ start, int* __restrict__ cnt,
                          int* __restrict__ csr, int E, int N) {
    int e = blockIdx.x * blockDim.x + threadIdx.x;
    if (e >= E) return;
    int r = blockIdx.y;
    const int* A = (r == 0) ? A1 : (r == 1) ? A2 : A3;
    int src = A[e], dst = A[E + e];
    int pos = start[(size_t)r * N + dst] + atomicAdd(&cnt[(size_t)r * N + dst], 1);
    csr[(size_t)r * E + pos] = src;
}

// ==================== layer 1: linear + scores + global-max fused ====================
// writes h as bf16 (for the gather-heavy agg1), scores fp32
__global__ void k_linear1(const float* __restrict__ X,
                          const float* __restrict__ W1, const float* __restrict__ W2,
                          const float* __restrict__ W3,
                          const float* __restrict__ as1, const float* __restrict__ ad1,
                          const float* __restrict__ as2, const float* __restrict__ ad2,
                          const float* __restrict__ as3, const float* __restrict__ ad3,
                          unsigned short* __restrict__ h_bf,
                          float* __restrict__ s_src, float* __restrict__ s_dst,
                          float* __restrict__ Mg, int N) {
    __shared__ float Xs[16][64];
    __shared__ float MgLoc[24];
    int t = threadIdx.x;
    if (t < 24) MgLoc[t] = -INFINITY;
    int n0 = blockIdx.x * 16;
    {
        int nl = t >> 4, k4 = t & 15;
        int n = n0 + nl;
        float4 xv = make_float4(0.f, 0.f, 0.f, 0.f);
        if (n < N) xv = reinterpret_cast<const float4*>(X + (size_t)n * 64)[k4];
        reinterpret_cast<float4*>(&Xs[nl][0])[k4] = xv;
    }
    __syncthreads();
    for (int g = t; g < 16 * 96; g += 256) {
        int nl = g / 96;
        int cg = g - nl * 96;
        int n = n0 + nl;
        int r = cg >> 5;
        int c4 = cg & 31;
        int head = c4 >> 2;
        int q = c4 & 3;
        float4 a = make_float4(0.f, 0.f, 0.f, 0.f);
        if (n < N) {
            const float* W = (r == 0) ? W1 : (r == 1) ? W2 : W3;
            const float4* Wv = reinterpret_cast<const float4*>(W) + c4;
            #pragma unroll
            for (int k = 0; k < 64; ++k) {
                float x = Xs[nl][k];
                float4 wv = Wv[(size_t)k * 32];
                a.x = fmaf(x, wv.x, a.x); a.y = fmaf(x, wv.y, a.y);
                a.z = fmaf(x, wv.z, a.z); a.w = fmaf(x, wv.w, a.w);
            }
            ushort4 hv;
            hv.x = f2bf(a.x); hv.y = f2bf(a.y); hv.z = f2bf(a.z); hv.w = f2bf(a.w);
            reinterpret_cast<ushort4*>(h_bf + (size_t)n * 384 + r * 128)[c4] = hv;
        }
        // fused attention scores: quad-reduce over the 4 threads of this head
        const float* As = ((r == 0) ? as1 : (r == 1) ? as2 : as3) + head * 16 + q * 4;
        const float* Ad = ((r == 0) ? ad1 : (r == 1) ? ad2 : ad3) + head * 16 + q * 4;
        float ss = a.x * As[0] + a.y * As[1] + a.z * As[2] + a.w * As[3];
        float sd = a.x * Ad[0] + a.y * Ad[1] + a.z * Ad[2] + a.w * Ad[3];
        ss += __shfl_xor(ss, 1); ss += __shfl_xor(ss, 2);
        sd += __shfl_xor(sd, 1); sd += __shfl_xor(sd, 2);
        if (q == 0 && n < N) {
            int rh = r * 8 + head;
            s_src[(size_t)n * 24 + rh] = ss;
            s_dst[(size_t)n * 24 + rh] = sd;
            atomicMaxF(&MgLoc[rh], ss);
        }
    }
    __syncthreads();
    if (t < 24) atomicMaxF(&Mg[t], MgLoc[t]);
}

// single-pass aggregation: block = (dst n, branch r), 128 threads = head*16+ch
__global__ void k_agg1(const unsigned short* __restrict__ h_bf,
                       const float* __restrict__ s_src, const float* __restrict__ s_dst,
                       const float* __restrict__ Mg,
                       const int* __restrict__ deg, const int* __restrict__ start,
                       const int* __restrict__ csr,
                       const float* __restrict__ b1, const float* __restrict__ b2,
                       const float* __restrict__ b3,
                       float* __restrict__ Xc, int E, int N) {
    __shared__ int sidx[128];
    __shared__ float sex[128 * 8];
    int n = blockIdx.x;
    int r = blockIdx.y;
    int j = threadIdx.x;
    int h = j >> 4;
    int rh = r * 8 + h;
    int s0 = start[(size_t)r * N + n];
    int d  = deg[(size_t)r * N + n];
    float sd = s_dst[(size_t)n * 24 + rh];
    float bound = lrelu(Mg[rh] + sd);
    float ex0 = __expf(lrelu(s_src[(size_t)n * 24 + rh] + sd) - bound);
    float denom = ex0;
    float acc = ex0 * bf2f(h_bf[(size_t)n * 384 + r * 128 + j]);
    int hA = j & 7;
    float sdA = s_dst[(size_t)n * 24 + r * 8 + hA];
    float bndA = lrelu(Mg[r * 8 + hA] + sdA);
    const int* cs = csr + (size_t)r * E + s0;
    for (int c0 = 0; c0 < d; c0 += 128) {
        int dc = min(128, d - c0);
        if (j < dc) sidx[j] = cs[c0 + j];
        __syncthreads();
        // phase A: one exp per (neighbor, head)
        for (int p = j; p < dc * 8; p += 128) {
            int i = p >> 3;
            float ssv = s_src[(size_t)sidx[i] * 24 + r * 8 + hA];
            sex[p] = __expf(lrelu(ssv + sdA) - bndA);
        }
        __syncthreads();
        // phase B: gather + accumulate (bf16 rows, 256B per neighbor)
        for (int i = 0; i < dc; ++i) {
            float ex = sex[i * 8 + h];
            int src = sidx[i];
            denom += ex;
            acc = fmaf(ex, bf2f(h_bf[(size_t)src * 384 + r * 128 + j]), acc);
        }
        __syncthreads();
    }
    const float* b = (r == 0) ? b1 : (r == 1) ? b2 : b3;
    float out = acc / (denom + 1e-16f) + b[j];
    Xc[(size_t)n * 384 + r * 128 + j] = (out > 0.f) ? out : 0.f;
}

// ==================== layer 2: linear + branch min/max fused ====================
// blockDim 1024 = 16 nodes (one wave each)
__global__ void k_linear2(const float* __restrict__ Xc,
                          const float* __restrict__ W1, const float* __restrict__ W2,
                          const float* __restrict__ W3,
                          float* __restrict__ h2, float* __restrict__ M2, int N) {
    __shared__ float redmx[16][3], redmn[16][3];
    int gid = blockIdx.x * 1024 + threadIdx.x;
    int node = gid >> 6;
    int lane = gid & 63;
    int wv = threadIdx.x >> 6;
    float s0 = 0.f, s1 = 0.f, s2 = 0.f;
    if (node < N) {
        const float* xp = Xc + (size_t)node * 384;
        #pragma unroll
        for (int j0 = 0; j0 < 384; j0 += 64) {
            float x = xp[j0 + lane];
            s0 = fmaf(x, W1[j0 + lane], s0);
            s1 = fmaf(x, W2[j0 + lane], s1);
            s2 = fmaf(x, W3[j0 + lane], s2);
        }
    }
    #pragma unroll
    for (int off = 32; off > 0; off >>= 1) {
        s0 += __shfl_down(s0, off);
        s1 += __shfl_down(s1, off);
        s2 += __shfl_down(s2, off);
    }
    if (lane == 0) {
        if (node < N) {
            h2[(size_t)node * 3 + 0] = s0;
            h2[(size_t)node * 3 + 1] = s1;
            h2[(size_t)node * 3 + 2] = s2;
            redmx[wv][0] = s0; redmx[wv][1] = s1; redmx[wv][2] = s2;
            redmn[wv][0] = s0; redmn[wv][1] = s1; redmn[wv][2] = s2;
        } else {
            redmx[wv][0] = redmx[wv][1] = redmx[wv][2] = -INFINITY;
            redmn[wv][0] = redmn[wv][1] = redmn[wv][2] = INFINITY;
        }
    }
    __syncthreads();
    if (threadIdx.x < 3) {
        float m = -INFINITY;
        for (int w2 = 0; w2 < 16; ++w2) m = fmaxf(m, redmx[w2][threadIdx.x]);
        atomicMaxF(&M2[threadIdx.x], m);
    } else if (threadIdx.x < 6) {
        int rr = threadIdx.x - 3;
        float m = INFINITY;
        for (int w2 = 0; w2 < 16; ++w2) m = fminf(m, redmn[w2][rr]);
        atomicMinF(&M2[3 + rr], m);
    }
}

// layer-2 aggregation + final projection: one thread per (node, branch), blockDim 192
__global__ void k_agg2f(const float* __restrict__ h2,
                        const int* __restrict__ deg, const int* __restrict__ start,
                        const int* __restrict__ csr,
                        const float* __restrict__ as1, const float* __restrict__ ad1,
                        const float* __restrict__ as2, const float* __restrict__ ad2,
                        const float* __restrict__ as3, const float* __restrict__ ad3,
                        const float* __restrict__ b1, const float* __restrict__ b2,
                        const float* __restrict__ b3,
                        const float* __restrict__ M2,
                        const float* __restrict__ ln_w, const float* __restrict__ ln_b,
                        float* __restrict__ out, int E, int N) {
    __shared__ float ys[192];
    int id = blockIdx.x * 192 + threadIdx.x;
    bool valid = id < 3 * N;
    int n = id / 3;
    int r = id - 3 * n;
    float y = 0.f;
    if (valid) {
        float a_s = ((r == 0) ? as1 : (r == 1) ? as2 : as3)[0];
        float a_d = ((r == 0) ? ad1 : (r == 1) ? ad2 : ad3)[0];
        int s0 = start[(size_t)r * N + n];
        int d  = deg[(size_t)r * N + n];
        float hd = h2[id];
        float sd = a_d * hd;
        float bound = lrelu(fmaxf(a_s * M2[r], a_s * M2[3 + r]) + sd);
        float ev = __expf(lrelu(fmaf(a_s, hd, sd)) - bound);
        float denom = ev;
        float acc = ev * hd;
        const int* cs = csr + (size_t)r * E + s0;
        int i = 0;
        for (; i + 1 < d; i += 2) {
            int sA = cs[i], sB = cs[i + 1];
            float hva = h2[(size_t)sA * 3 + r];
            float hvb = h2[(size_t)sB * 3 + r];
            float eA = __expf(lrelu(fmaf(a_s, hva, sd)) - bound);
            float eB = __expf(lrelu(fmaf(a_s, hvb, sd)) - bound);
            denom += eA + eB;
            acc = fmaf(eA, hva, acc);
            acc = fmaf(eB, hvb, acc);
        }
        if (i < d) {
            float hva = h2[(size_t)cs[i] * 3 + r];
            float eA = __expf(lrelu(fmaf(a_s, hva, sd)) - bound);
            denom += eA;
            acc = fmaf(eA, hva, acc);
        }
        float b = ((r == 0) ? b1 : (r == 1) ? b2 : b3)[0];
        y = (acc / (denom + 1e-16f) + b) * ln_w[r];
    }
    ys[threadIdx.x] = y;
    __syncthreads();
    if (valid && r == 0)
        out[n] = ys[threadIdx.x] + ys[threadIdx.x + 1] + ys[threadIdx.x + 2] + ln_b[0];
}

extern "C" void kernel_launch(void* const* d_in, const int* in_sizes, int n_in,
                              void* d_out, int out_size, void* d_ws, size_t ws_size,
                              hipStream_t stream) {
    const float* X  = (const float*)d_in[0];
    const int*   A1 = (const int*)d_in[1];
    const int*   A2 = (const int*)d_in[2];
    const int*   A3 = (const int*)d_in[3];
    const float* W11 = (const float*)d_in[5];
    const float* as11 = (const float*)d_in[6];
    const float* ad11 = (const float*)d_in[7];
    const float* b11 = (const float*)d_in[8];
    const float* W12 = (const float*)d_in[9];
    const float* as12 = (const float*)d_in[10];
    const float* ad12 = (const float*)d_in[11];
    const float* b12 = (const float*)d_in[12];
    const float* W21 = (const float*)d_in[13];
    const float* as21 = (const float*)d_in[14];
    const float* ad21 = (const float*)d_in[15];
    const float* b21 = (const float*)d_in[16];
    const float* W22 = (const float*)d_in[17];
    const float* as22 = (const float*)d_in[18];
    const float* ad22 = (const float*)d_in[19];
    const float* b22 = (const float*)d_in[20];
    const float* W31 = (const float*)d_in[21];
    const float* as31 = (const float*)d_in[22];
    const float* ad31 = (const float*)d_in[23];
    const float* b31 = (const float*)d_in[24];
    const float* W32 = (const float*)d_in[25];
    const float* as32 = (const float*)d_in[26];
    const float* ad32 = (const float*)d_in[27];
    const float* b32 = (const float*)d_in[28];
    const float* ln_w = (const float*)d_in[29];
    const float* ln_b = (const float*)d_in[30];

    const int N = in_sizes[0] / 64;
    const int E = in_sizes[1] / 2;
    const int total = 3 * N;
    const int nbA = (total + 1023) / 1024;

    // workspace layout
    float* w = (float*)d_ws;
    float* Xc     = w; w += (size_t)N * 384;
    float* s_src1 = w; w += (size_t)N * 24;
    float* s_dst1 = w; w += (size_t)N * 24;
    float* h2     = w; w += (size_t)N * 3;
    float* Mg1    = w; w += 32;
    float* M2     = w; w += 8;
    unsigned short* h_bf = (unsigned short*)w; w += (size_t)N * 192;  // N*384 ushorts
    int* iw    = (int*)w;
    int* deg   = iw; iw += (size_t)3 * N;
    int* cnt   = iw; iw += (size_t)3 * N;   // contiguous with deg -> one memset
    int* start = iw; iw += (size_t)3 * N;
    int* bsum  = iw; iw += 1024;
    int* csr   = iw; iw += (size_t)3 * E;

    const int BLK = 256;

    // ---- CSR build (shared by both layers) ----
    hipMemsetAsync(deg, 0, (size_t)6 * N * sizeof(int), stream);
    {
        dim3 grid((E + BLK - 1) / BLK, 3);
        k_deg<<<grid, BLK, 0, stream>>>(A1, A2, A3, deg, E, N);
        k_scanA<<<nbA, 256, 0, stream>>>(deg, start, bsum, total);
        k_scanB<<<1, 256, 0, stream>>>(bsum, nbA, Mg1, M2);
        k_scanC<<<(total + BLK - 1) / BLK, BLK, 0, stream>>>(start, bsum, total, N, E);
        k_scatter<<<grid, BLK, 0, stream>>>(A1, A2, A3, start, cnt, csr, E, N);
    }

    // ---- layer 1 ----
    k_linear1<<<(N + 15) / 16, BLK, 0, stream>>>(
        X, W11, W21, W31, as11, ad11, as21, ad21, as31, ad31,
        h_bf, s_src1, s_dst1, Mg1, N);
    {
        dim3 grid(N, 3);
        k_agg1<<<grid, 128, 0, stream>>>(h_bf, s_src1, s_dst1, Mg1, deg, start, csr,
                                         b11, b21, b31, Xc, E, N);
    }

    // ---- layer 2 ----
    k_linear2<<<(N + 15) / 16, 1024, 0, stream>>>(Xc, W12, W22, W32, h2, M2, N);
    {
        int nb = (total + 191) / 192;
        k_agg2f<<<nb, 192, 0, stream>>>(
            h2, deg, start, csr,
            as12, ad12, as22, ad22, as32, ad32,
            b12, b22, b32, M2, ln_w, ln_b, (float*)d_out, E, N);
    }
}

// Round 7
// 661.690 us; speedup vs baseline: 29.1395x; 1.0404x over previous
//
#include <hip/hip_runtime.h>
#include <cstdint>
#include <cstddef>

#define NEG_SLOPE 0.2f

__device__ __forceinline__ float lrelu(float v) { return v >= 0.f ? v : NEG_SLOPE * v; }

__device__ __forceinline__ void atomicMaxF(float* addr, float val) {
    if (val >= 0.0f) atomicMax((int*)addr, __float_as_int(val));
    else             atomicMin((unsigned int*)addr, __float_as_uint(val));
}
__device__ __forceinline__ void atomicMinF(float* addr, float val) {
    if (val >= 0.0f) atomicMin((int*)addr, __float_as_int(val));
    else             atomicMax((unsigned int*)addr, __float_as_uint(val));
}

// bf16 pack/unpack (round-to-nearest-even)
__device__ __forceinline__ unsigned short f2bf(float x) {
    union { float f; uint32_t u; } v; v.f = x;
    uint32_t r = v.u + 0x7FFFu + ((v.u >> 16) & 1u);
    return (unsigned short)(r >> 16);
}
__device__ __forceinline__ float bf2f(unsigned short h) {
    union { uint32_t u; float f; } v; v.u = (uint32_t)h << 16;
    return v.f;
}

// ==================== CSR build ====================
__global__ void k_deg(const int* __restrict__ A1, const int* __restrict__ A2,
                      const int* __restrict__ A3, int* __restrict__ deg, int E, int N) {
    int e = blockIdx.x * blockDim.x + threadIdx.x;
    if (e >= E) return;
    int r = blockIdx.y;
    const int* A = (r == 0) ? A1 : (r == 1) ? A2 : A3;
    atomicAdd(&deg[(size_t)r * N + A[E + e]], 1);
}

__global__ void k_scanA(const int* __restrict__ deg, int* __restrict__ start,
                        int* __restrict__ bsum, int total) {
    __shared__ int tmp[256];
    int t = threadIdx.x;
    int base = blockIdx.x * 1024 + t * 4;
    int v[4]; int s = 0;
    #pragma unroll
    for (int k = 0; k < 4; ++k) { v[k] = (base + k < total) ? deg[base + k] : 0; s += v[k]; }
    tmp[t] = s; __syncthreads();
    for (int off = 1; off < 256; off <<= 1) {
        int x = (t >= off) ? tmp[t - off] : 0; __syncthreads();
        tmp[t] += x; __syncthreads();
    }
    int run = tmp[t] - s;
    #pragma unroll
    for (int k = 0; k < 4; ++k) {
        if (base + k < total) start[base + k] = run;
        run += v[k];
    }
    if (t == 255) bsum[blockIdx.x] = tmp[255];
}

// one block; also re-initializes Mg1/M2 (runs before linear kernels in-stream)
__global__ void k_scanB(int* __restrict__ bsum, int nb,
                        float* __restrict__ Mg, float* __restrict__ M2) {
    __shared__ int tmp[256];
    int t = threadIdx.x;
    if (t < 24) Mg[t] = -INFINITY;
    else if (t < 27) M2[t - 24] = -INFINITY;   // M2[0..2] = branch max
    else if (t < 30) M2[t - 24] = INFINITY;    // M2[3..5] = branch min
    int v[4]; int s = 0;
    #pragma unroll
    for (int k = 0; k < 4; ++k) { int i = t * 4 + k; v[k] = (i < nb) ? bsum[i] : 0; s += v[k]; }
    tmp[t] = s; __syncthreads();
    for (int off = 1; off < 256; off <<= 1) {
        int x = (t >= off) ? tmp[t - off] : 0; __syncthreads();
        tmp[t] += x; __syncthreads();
    }
    int run = tmp[t] - s;
    #pragma unroll
    for (int k = 0; k < 4; ++k) {
        int i = t * 4 + k;
        if (i < nb) { int vv = v[k]; bsum[i] = run; run += vv; }
    }
}

__global__ void k_scanC(int* __restrict__ start, const int* __restrict__ bsum,
                        int total, int N, int E) {
    int g = blockIdx.x * blockDim.x + threadIdx.x;
    if (g >= total) return;
    int r = g / N;
    start[g] += bsum[g >> 10] - r * E;
}

__global__ void k_scatter(const int* __restrict__ A1, const int* __restrict__ A2,
                          const int* __restrict__ A3,
                          const int* __restrict__ start, int* __restrict__ cnt,
                          int* __restrict__ csr, int E, int N) {
    int e = blockIdx.x * blockDim.x + threadIdx.x;
    if (e >= E) return;
    int r = blockIdx.y;
    const int* A = (r == 0) ? A1 : (r == 1) ? A2 : A3;
    int src = A[e], dst = A[E + e];
    int pos = start[(size_t)r * N + dst] + atomicAdd(&cnt[(size_t)r * N + dst], 1);
    csr[(size_t)r * E + pos] = src;
}

// ==================== layer 1: register-W linear + scores + global-max ====================
// 384 threads = one W column each (r = t>>7, col = t&127); 64-node tile in LDS.
// W column cached in 64 VGPRs, reused across all 64 nodes -> no W re-read traffic.
#define L1_NODES 64
__global__ __launch_bounds__(384) void k_linear1(
        const float* __restrict__ X,
        const float* __restrict__ W1, const float* __restrict__ W2,
        const float* __restrict__ W3,
        const float* __restrict__ as1, const float* __restrict__ ad1,
        const float* __restrict__ as2, const float* __restrict__ ad2,
        const float* __restrict__ as3, const float* __restrict__ ad3,
        unsigned short* __restrict__ h_bf,
        float* __restrict__ s_src, float* __restrict__ s_dst,
        float* __restrict__ Mg, int N) {
    __shared__ float Xs[L1_NODES][64];
    int t = threadIdx.x;
    int n0 = blockIdx.x * L1_NODES;
    // stage X tile
    {
        const float4* X4 = reinterpret_cast<const float4*>(X);
        float4* Xs4 = reinterpret_cast<float4*>(&Xs[0][0]);
        for (int i = t; i < L1_NODES * 16; i += 384) {
            int nl = i >> 4;
            float4 xv = make_float4(0.f, 0.f, 0.f, 0.f);
            if (n0 + nl < N) xv = X4[(size_t)(n0 + nl) * 16 + (i & 15)];
            Xs4[i] = xv;
        }
    }
    int r = t >> 7, col = t & 127, head = (t >> 4) & 7, c = t & 15;
    const float* Wp = ((r == 0) ? W1 : (r == 1) ? W2 : W3) + col;
    float Wc[64];
    #pragma unroll
    for (int k = 0; k < 64; ++k) Wc[k] = Wp[(size_t)k * 128];
    float as_v = ((r == 0) ? as1 : (r == 1) ? as2 : as3)[head * 16 + c];
    float ad_v = ((r == 0) ? ad1 : (r == 1) ? ad2 : ad3)[head * 16 + c];
    __syncthreads();
    int nmax = min(L1_NODES, N - n0);
    float mgm = -INFINITY;
    int rh = (r << 3) + head;
    for (int n = 0; n < nmax; ++n) {
        const float4* xr = reinterpret_cast<const float4*>(&Xs[n][0]);
        float a0 = 0.f, a1 = 0.f, a2 = 0.f, a3 = 0.f;
        #pragma unroll
        for (int k4 = 0; k4 < 16; ++k4) {
            float4 xv = xr[k4];
            a0 = fmaf(xv.x, Wc[k4 * 4 + 0], a0);
            a1 = fmaf(xv.y, Wc[k4 * 4 + 1], a1);
            a2 = fmaf(xv.z, Wc[k4 * 4 + 2], a2);
            a3 = fmaf(xv.w, Wc[k4 * 4 + 3], a3);
        }
        float acc = (a0 + a1) + (a2 + a3);
        h_bf[(size_t)(n0 + n) * 384 + t] = f2bf(acc);
        float ss = acc * as_v, sd = acc * ad_v;
        ss += __shfl_xor(ss, 1); ss += __shfl_xor(ss, 2);
        ss += __shfl_xor(ss, 4); ss += __shfl_xor(ss, 8);
        sd += __shfl_xor(sd, 1); sd += __shfl_xor(sd, 2);
        sd += __shfl_xor(sd, 4); sd += __shfl_xor(sd, 8);
        if (c == 0) {
            s_src[(size_t)(n0 + n) * 24 + rh] = ss;
            s_dst[(size_t)(n0 + n) * 24 + rh] = sd;
            mgm = fmaxf(mgm, ss);
        }
    }
    if (c == 0) atomicMaxF(&Mg[rh], mgm);
}

// single-pass aggregation: block = (dst n, branch r), 128 threads = head*16+ch
__global__ void k_agg1(const unsigned short* __restrict__ h_bf,
                       const float* __restrict__ s_src, const float* __restrict__ s_dst,
                       const float* __restrict__ Mg,
                       const int* __restrict__ deg, const int* __restrict__ start,
                       const int* __restrict__ csr,
                       const float* __restrict__ b1, const float* __restrict__ b2,
                       const float* __restrict__ b3,
                       unsigned short* __restrict__ Xc, int E, int N) {
    __shared__ int sidx[128];
    __shared__ float sex[128 * 8];
    int n = blockIdx.x;
    int r = blockIdx.y;
    int j = threadIdx.x;
    int h = j >> 4;
    int rh = r * 8 + h;
    int s0 = start[(size_t)r * N + n];
    int d  = deg[(size_t)r * N + n];
    float sd = s_dst[(size_t)n * 24 + rh];
    float bound = lrelu(Mg[rh] + sd);
    float ex0 = __expf(lrelu(s_src[(size_t)n * 24 + rh] + sd) - bound);
    float denom = ex0;
    float acc = ex0 * bf2f(h_bf[(size_t)n * 384 + r * 128 + j]);
    int hA = j & 7;
    float sdA = s_dst[(size_t)n * 24 + r * 8 + hA];
    float bndA = lrelu(Mg[r * 8 + hA] + sdA);
    const int* cs = csr + (size_t)r * E + s0;
    for (int c0 = 0; c0 < d; c0 += 128) {
        int dc = min(128, d - c0);
        if (j < dc) sidx[j] = cs[c0 + j];
        __syncthreads();
        // phase A: one exp per (neighbor, head)
        for (int p = j; p < dc * 8; p += 128) {
            int i = p >> 3;
            float ssv = s_src[(size_t)sidx[i] * 24 + r * 8 + hA];
            sex[p] = __expf(lrelu(ssv + sdA) - bndA);
        }
        __syncthreads();
        // phase B: gather + accumulate (bf16 rows, 256B per neighbor)
        for (int i = 0; i < dc; ++i) {
            float ex = sex[i * 8 + h];
            int src = sidx[i];
            denom += ex;
            acc = fmaf(ex, bf2f(h_bf[(size_t)src * 384 + r * 128 + j]), acc);
        }
        __syncthreads();
    }
    const float* b = (r == 0) ? b1 : (r == 1) ? b2 : b3;
    float out = acc / (denom + 1e-16f) + b[j];
    Xc[(size_t)n * 384 + r * 128 + j] = f2bf((out > 0.f) ? out : 0.f);
}

// ==================== layer 2: linear + branch min/max fused ====================
// blockDim 1024 = 16 nodes (one wave each); Xc is bf16
__global__ void k_linear2(const unsigned short* __restrict__ Xc,
                          const float* __restrict__ W1, const float* __restrict__ W2,
                          const float* __restrict__ W3,
                          float* __restrict__ h2, float* __restrict__ M2, int N) {
    __shared__ float redmx[16][3], redmn[16][3];
    int gid = blockIdx.x * 1024 + threadIdx.x;
    int node = gid >> 6;
    int lane = gid & 63;
    int wv = threadIdx.x >> 6;
    float s0 = 0.f, s1 = 0.f, s2 = 0.f;
    if (node < N) {
        const unsigned short* xp = Xc + (size_t)node * 384;
        #pragma unroll
        for (int j0 = 0; j0 < 384; j0 += 64) {
            float x = bf2f(xp[j0 + lane]);
            s0 = fmaf(x, W1[j0 + lane], s0);
            s1 = fmaf(x, W2[j0 + lane], s1);
            s2 = fmaf(x, W3[j0 + lane], s2);
        }
    }
    #pragma unroll
    for (int off = 32; off > 0; off >>= 1) {
        s0 += __shfl_down(s0, off);
        s1 += __shfl_down(s1, off);
        s2 += __shfl_down(s2, off);
    }
    if (lane == 0) {
        if (node < N) {
            h2[(size_t)node * 3 + 0] = s0;
            h2[(size_t)node * 3 + 1] = s1;
            h2[(size_t)node * 3 + 2] = s2;
            redmx[wv][0] = s0; redmx[wv][1] = s1; redmx[wv][2] = s2;
            redmn[wv][0] = s0; redmn[wv][1] = s1; redmn[wv][2] = s2;
        } else {
            redmx[wv][0] = redmx[wv][1] = redmx[wv][2] = -INFINITY;
            redmn[wv][0] = redmn[wv][1] = redmn[wv][2] = INFINITY;
        }
    }
    __syncthreads();
    if (threadIdx.x < 3) {
        float m = -INFINITY;
        for (int w2 = 0; w2 < 16; ++w2) m = fmaxf(m, redmx[w2][threadIdx.x]);
        atomicMaxF(&M2[threadIdx.x], m);
    } else if (threadIdx.x < 6) {
        int rr = threadIdx.x - 3;
        float m = INFINITY;
        for (int w2 = 0; w2 < 16; ++w2) m = fminf(m, redmn[w2][rr]);
        atomicMinF(&M2[3 + rr], m);
    }
}

// layer-2 aggregation + final projection: one thread per (node, branch), blockDim 192
__global__ void k_agg2f(const float* __restrict__ h2,
                        const int* __restrict__ deg, const int* __restrict__ start,
                        const int* __restrict__ csr,
                        const float* __restrict__ as1, const float* __restrict__ ad1,
                        const float* __restrict__ as2, const float* __restrict__ ad2,
                        const float* __restrict__ as3, const float* __restrict__ ad3,
                        const float* __restrict__ b1, const float* __restrict__ b2,
                        const float* __restrict__ b3,
                        const float* __restrict__ M2,
                        const float* __restrict__ ln_w, const float* __restrict__ ln_b,
                        float* __restrict__ out, int E, int N) {
    __shared__ float ys[192];
    int id = blockIdx.x * 192 + threadIdx.x;
    bool valid = id < 3 * N;
    int n = id / 3;
    int r = id - 3 * n;
    float y = 0.f;
    if (valid) {
        float a_s = ((r == 0) ? as1 : (r == 1) ? as2 : as3)[0];
        float a_d = ((r == 0) ? ad1 : (r == 1) ? ad2 : ad3)[0];
        int s0 = start[(size_t)r * N + n];
        int d  = deg[(size_t)r * N + n];
        float hd = h2[id];
        float sd = a_d * hd;
        float bound = lrelu(fmaxf(a_s * M2[r], a_s * M2[3 + r]) + sd);
        float ev = __expf(lrelu(fmaf(a_s, hd, sd)) - bound);
        float denom = ev;
        float acc = ev * hd;
        const int* cs = csr + (size_t)r * E + s0;
        int i = 0;
        for (; i + 1 < d; i += 2) {
            int sA = cs[i], sB = cs[i + 1];
            float hva = h2[(size_t)sA * 3 + r];
            float hvb = h2[(size_t)sB * 3 + r];
            float eA = __expf(lrelu(fmaf(a_s, hva, sd)) - bound);
            float eB = __expf(lrelu(fmaf(a_s, hvb, sd)) - bound);
            denom += eA + eB;
            acc = fmaf(eA, hva, acc);
            acc = fmaf(eB, hvb, acc);
        }
        if (i < d) {
            float hva = h2[(size_t)cs[i] * 3 + r];
            float eA = __expf(lrelu(fmaf(a_s, hva, sd)) - bound);
            denom += eA;
            acc = fmaf(eA, hva, acc);
        }
        float b = ((r == 0) ? b1 : (r == 1) ? b2 : b3)[0];
        y = (acc / (denom + 1e-16f) + b) * ln_w[r];
    }
    ys[threadIdx.x] = y;
    __syncthreads();
    if (valid && r == 0)
        out[n] = ys[threadIdx.x] + ys[threadIdx.x + 1] + ys[threadIdx.x + 2] + ln_b[0];
}

extern "C" void kernel_launch(void* const* d_in, const int* in_sizes, int n_in,
                              void* d_out, int out_size, void* d_ws, size_t ws_size,
                              hipStream_t stream) {
    const float* X  = (const float*)d_in[0];
    const int*   A1 = (const int*)d_in[1];
    const int*   A2 = (const int*)d_in[2];
    const int*   A3 = (const int*)d_in[3];
    const float* W11 = (const float*)d_in[5];
    const float* as11 = (const float*)d_in[6];
    const float* ad11 = (const float*)d_in[7];
    const float* b11 = (const float*)d_in[8];
    const float* W12 = (const float*)d_in[9];
    const float* as12 = (const float*)d_in[10];
    const float* ad12 = (const float*)d_in[11];
    const float* b12 = (const float*)d_in[12];
    const float* W21 = (const float*)d_in[13];
    const float* as21 = (const float*)d_in[14];
    const float* ad21 = (const float*)d_in[15];
    const float* b21 = (const float*)d_in[16];
    const float* W22 = (const float*)d_in[17];
    const float* as22 = (const float*)d_in[18];
    const float* ad22 = (const float*)d_in[19];
    const float* b22 = (const float*)d_in[20];
    const float* W31 = (const float*)d_in[21];
    const float* as31 = (const float*)d_in[22];
    const float* ad31 = (const float*)d_in[23];
    const float* b31 = (const float*)d_in[24];
    const float* W32 = (const float*)d_in[25];
    const float* as32 = (const float*)d_in[26];
    const float* ad32 = (const float*)d_in[27];
    const float* b32 = (const float*)d_in[28];
    const float* ln_w = (const float*)d_in[29];
    const float* ln_b = (const float*)d_in[30];

    const int N = in_sizes[0] / 64;
    const int E = in_sizes[1] / 2;
    const int total = 3 * N;
    const int nbA = (total + 1023) / 1024;

    // workspace layout
    float* w = (float*)d_ws;
    float* s_src1 = w; w += (size_t)N * 24;
    float* s_dst1 = w; w += (size_t)N * 24;
    float* h2     = w; w += (size_t)N * 3;
    float* Mg1    = w; w += 32;
    float* M2     = w; w += 8;
    unsigned short* h_bf = (unsigned short*)w; w += (size_t)N * 192;  // N*384 bf16
    unsigned short* Xc   = (unsigned short*)w; w += (size_t)N * 192;  // N*384 bf16
    int* iw    = (int*)w;
    int* deg   = iw; iw += (size_t)3 * N;
    int* cnt   = iw; iw += (size_t)3 * N;   // contiguous with deg -> one memset
    int* start = iw; iw += (size_t)3 * N;
    int* bsum  = iw; iw += 1024;
    int* csr   = iw; iw += (size_t)3 * E;

    const int BLK = 256;

    // ---- CSR build (shared by both layers) ----
    hipMemsetAsync(deg, 0, (size_t)6 * N * sizeof(int), stream);
    {
        dim3 grid((E + BLK - 1) / BLK, 3);
        k_deg<<<grid, BLK, 0, stream>>>(A1, A2, A3, deg, E, N);
        k_scanA<<<nbA, 256, 0, stream>>>(deg, start, bsum, total);
        k_scanB<<<1, 256, 0, stream>>>(bsum, nbA, Mg1, M2);
        k_scanC<<<(total + BLK - 1) / BLK, BLK, 0, stream>>>(start, bsum, total, N, E);
        k_scatter<<<grid, BLK, 0, stream>>>(A1, A2, A3, start, cnt, csr, E, N);
    }

    // ---- layer 1 ----
    k_linear1<<<(N + L1_NODES - 1) / L1_NODES, 384, 0, stream>>>(
        X, W11, W21, W31, as11, ad11, as21, ad21, as31, ad31,
        h_bf, s_src1, s_dst1, Mg1, N);
    {
        dim3 grid(N, 3);
        k_agg1<<<grid, 128, 0, stream>>>(h_bf, s_src1, s_dst1, Mg1, deg, start, csr,
                                         b11, b21, b31, Xc, E, N);
    }

    // ---- layer 2 ----
    k_linear2<<<(N + 15) / 16, 1024, 0, stream>>>(Xc, W12, W22, W32, h2, M2, N);
    {
        int nb = (total + 191) / 192;
        k_agg2f<<<nb, 192, 0, stream>>>(
            h2, deg, start, csr,
            as12, ad12, as22, ad22, as32, ad32,
            b12, b22, b32, M2, ln_w, ln_b, (float*)d_out, E, N);
    }
}

// Round 8
// 644.698 us; speedup vs baseline: 29.9075x; 1.0264x over previous
//
#include <hip/hip_runtime.h>
#include <cstdint>
#include <cstddef>

#define NEG_SLOPE 0.2f

__device__ __forceinline__ float lrelu(float v) { return v >= 0.f ? v : NEG_SLOPE * v; }

__device__ __forceinline__ void atomicMaxF(float* addr, float val) {
    if (val >= 0.0f) atomicMax((int*)addr, __float_as_int(val));
    else             atomicMin((unsigned int*)addr, __float_as_uint(val));
}
__device__ __forceinline__ void atomicMinF(float* addr, float val) {
    if (val >= 0.0f) atomicMin((int*)addr, __float_as_int(val));
    else             atomicMax((unsigned int*)addr, __float_as_uint(val));
}

// bf16 pack/unpack (round-to-nearest-even)
__device__ __forceinline__ unsigned short f2bf(float x) {
    union { float f; uint32_t u; } v; v.f = x;
    uint32_t r = v.u + 0x7FFFu + ((v.u >> 16) & 1u);
    return (unsigned short)(r >> 16);
}
__device__ __forceinline__ float bf2f(unsigned short h) {
    union { uint32_t u; float f; } v; v.u = (uint32_t)h << 16;
    return v.f;
}
__device__ __forceinline__ float bf2f_lo(uint32_t u) {
    union { uint32_t u; float f; } v; v.u = u << 16;
    return v.f;
}
__device__ __forceinline__ float bf2f_hi(uint32_t u) {
    union { uint32_t u; float f; } v; v.u = u & 0xFFFF0000u;
    return v.f;
}

// ==================== CSR build ====================
__global__ void k_deg(const int* __restrict__ A1, const int* __restrict__ A2,
                      const int* __restrict__ A3, int* __restrict__ deg, int E, int N) {
    int e = blockIdx.x * blockDim.x + threadIdx.x;
    if (e >= E) return;
    int r = blockIdx.y;
    const int* A = (r == 0) ? A1 : (r == 1) ? A2 : A3;
    atomicAdd(&deg[(size_t)r * N + A[E + e]], 1);
}

__global__ void k_scanA(const int* __restrict__ deg, int* __restrict__ start,
                        int* __restrict__ bsum, int total) {
    __shared__ int tmp[256];
    int t = threadIdx.x;
    int base = blockIdx.x * 1024 + t * 4;
    int v[4]; int s = 0;
    #pragma unroll
    for (int k = 0; k < 4; ++k) { v[k] = (base + k < total) ? deg[base + k] : 0; s += v[k]; }
    tmp[t] = s; __syncthreads();
    for (int off = 1; off < 256; off <<= 1) {
        int x = (t >= off) ? tmp[t - off] : 0; __syncthreads();
        tmp[t] += x; __syncthreads();
    }
    int run = tmp[t] - s;
    #pragma unroll
    for (int k = 0; k < 4; ++k) {
        if (base + k < total) start[base + k] = run;
        run += v[k];
    }
    if (t == 255) bsum[blockIdx.x] = tmp[255];
}

// one block; also re-initializes Mg1/M2 (runs before linear kernels in-stream)
__global__ void k_scanB(int* __restrict__ bsum, int nb,
                        float* __restrict__ Mg, float* __restrict__ M2) {
    __shared__ int tmp[256];
    int t = threadIdx.x;
    if (t < 24) Mg[t] = -INFINITY;
    else if (t < 27) M2[t - 24] = -INFINITY;   // M2[0..2] = branch max
    else if (t < 30) M2[t - 24] = INFINITY;    // M2[3..5] = branch min
    int v[4]; int s = 0;
    #pragma unroll
    for (int k = 0; k < 4; ++k) { int i = t * 4 + k; v[k] = (i < nb) ? bsum[i] : 0; s += v[k]; }
    tmp[t] = s; __syncthreads();
    for (int off = 1; off < 256; off <<= 1) {
        int x = (t >= off) ? tmp[t - off] : 0; __syncthreads();
        tmp[t] += x; __syncthreads();
    }
    int run = tmp[t] - s;
    #pragma unroll
    for (int k = 0; k < 4; ++k) {
        int i = t * 4 + k;
        if (i < nb) { int vv = v[k]; bsum[i] = run; run += vv; }
    }
}

__global__ void k_scanC(int* __restrict__ start, const int* __restrict__ bsum,
                        int total, int N, int E) {
    int g = blockIdx.x * blockDim.x + threadIdx.x;
    if (g >= total) return;
    int r = g / N;
    start[g] += bsum[g >> 10] - r * E;
}

__global__ void k_scatter(const int* __restrict__ A1, const int* __restrict__ A2,
                          const int* __restrict__ A3,
                          const int* __restrict__ start, int* __restrict__ cnt,
                          int* __restrict__ csr, int E, int N) {
    int e = blockIdx.x * blockDim.x + threadIdx.x;
    if (e >= E) return;
    int r = blockIdx.y;
    const int* A = (r == 0) ? A1 : (r == 1) ? A2 : A3;
    int src = A[e], dst = A[E + e];
    int pos = start[(size_t)r * N + dst] + atomicAdd(&cnt[(size_t)r * N + dst], 1);
    csr[(size_t)r * E + pos] = src;
}

// ==================== layer 1: register-W linear + scores + global-max ====================
#define L1_NODES 64
__global__ __launch_bounds__(384) void k_linear1(
        const float* __restrict__ X,
        const float* __restrict__ W1, const float* __restrict__ W2,
        const float* __restrict__ W3,
        const float* __restrict__ as1, const float* __restrict__ ad1,
        const float* __restrict__ as2, const float* __restrict__ ad2,
        const float* __restrict__ as3, const float* __restrict__ ad3,
        unsigned short* __restrict__ h_bf,
        float* __restrict__ s_src, float* __restrict__ s_dst,
        float* __restrict__ Mg, int N) {
    __shared__ float Xs[L1_NODES][64];
    int t = threadIdx.x;
    int n0 = blockIdx.x * L1_NODES;
    {
        const float4* X4 = reinterpret_cast<const float4*>(X);
        float4* Xs4 = reinterpret_cast<float4*>(&Xs[0][0]);
        for (int i = t; i < L1_NODES * 16; i += 384) {
            int nl = i >> 4;
            float4 xv = make_float4(0.f, 0.f, 0.f, 0.f);
            if (n0 + nl < N) xv = X4[(size_t)(n0 + nl) * 16 + (i & 15)];
            Xs4[i] = xv;
        }
    }
    int r = t >> 7, col = t & 127, head = (t >> 4) & 7, c = t & 15;
    const float* Wp = ((r == 0) ? W1 : (r == 1) ? W2 : W3) + col;
    float Wc[64];
    #pragma unroll
    for (int k = 0; k < 64; ++k) Wc[k] = Wp[(size_t)k * 128];
    float as_v = ((r == 0) ? as1 : (r == 1) ? as2 : as3)[head * 16 + c];
    float ad_v = ((r == 0) ? ad1 : (r == 1) ? ad2 : ad3)[head * 16 + c];
    __syncthreads();
    int nmax = min(L1_NODES, N - n0);
    float mgm = -INFINITY;
    int rh = (r << 3) + head;
    for (int n = 0; n < nmax; ++n) {
        const float4* xr = reinterpret_cast<const float4*>(&Xs[n][0]);
        float a0 = 0.f, a1 = 0.f, a2 = 0.f, a3 = 0.f;
        #pragma unroll
        for (int k4 = 0; k4 < 16; ++k4) {
            float4 xv = xr[k4];
            a0 = fmaf(xv.x, Wc[k4 * 4 + 0], a0);
            a1 = fmaf(xv.y, Wc[k4 * 4 + 1], a1);
            a2 = fmaf(xv.z, Wc[k4 * 4 + 2], a2);
            a3 = fmaf(xv.w, Wc[k4 * 4 + 3], a3);
        }
        float acc = (a0 + a1) + (a2 + a3);
        h_bf[(size_t)(n0 + n) * 384 + t] = f2bf(acc);
        float ss = acc * as_v, sd = acc * ad_v;
        ss += __shfl_xor(ss, 1); ss += __shfl_xor(ss, 2);
        ss += __shfl_xor(ss, 4); ss += __shfl_xor(ss, 8);
        sd += __shfl_xor(sd, 1); sd += __shfl_xor(sd, 2);
        sd += __shfl_xor(sd, 4); sd += __shfl_xor(sd, 8);
        if (c == 0) {
            s_src[(size_t)(n0 + n) * 24 + rh] = ss;
            s_dst[(size_t)(n0 + n) * 24 + rh] = sd;
            mgm = fmaxf(mgm, ss);
        }
    }
    if (c == 0) atomicMaxF(&Mg[rh], mgm);
}

// ==================== layer-1 aggregation ====================
// block = (dst n, branch r), 64 threads; each thread owns a uint = 2 bf16 channels
__global__ __launch_bounds__(64) void k_agg1(
        const unsigned short* __restrict__ h_bf,
        const float* __restrict__ s_src, const float* __restrict__ s_dst,
        const float* __restrict__ Mg,
        const int* __restrict__ deg, const int* __restrict__ start,
        const int* __restrict__ csr,
        const float* __restrict__ b1, const float* __restrict__ b2,
        const float* __restrict__ b3,
        unsigned short* __restrict__ Xc, int E, int N) {
    __shared__ int sidx[64];
    __shared__ float sex[64 * 8];
    int n = blockIdx.x;
    int r = blockIdx.y;
    int j = threadIdx.x;              // uint channel-pair index 0..63
    int h = j >> 3;                   // head (16 ch = 8 uints per head)
    int rh = r * 8 + h;
    int s0 = start[(size_t)r * N + n];
    int d  = deg[(size_t)r * N + n];
    const uint32_t* hb = reinterpret_cast<const uint32_t*>(h_bf);
    float sd = s_dst[(size_t)n * 24 + rh];
    float bound = lrelu(Mg[rh] + sd);
    float ex0 = __expf(lrelu(s_src[(size_t)n * 24 + rh] + sd) - bound);
    float denom = ex0;
    uint32_t hv0 = hb[(size_t)n * 192 + r * 64 + j];
    float accx = ex0 * bf2f_lo(hv0);
    float accy = ex0 * bf2f_hi(hv0) * (1.0f / 65536.0f) * 65536.0f;  // keep simple
    // (bf2f_hi already returns the value; the multiply chain above is identity)
    accy = ex0 * bf2f_hi(hv0);
    int hA = j & 7;
    float sdA = s_dst[(size_t)n * 24 + r * 8 + hA];
    float bndA = lrelu(Mg[r * 8 + hA] + sdA);
    const int* cs = csr + (size_t)r * E + s0;
    for (int c0 = 0; c0 < d; c0 += 64) {
        int dc = min(64, d - c0);
        if (j < dc) sidx[j] = cs[c0 + j];
        __syncthreads();
        // phase A: one exp per (neighbor, head)
        for (int p = j; p < dc * 8; p += 64) {
            int i = p >> 3;
            float ssv = s_src[(size_t)sidx[i] * 24 + r * 8 + hA];
            sex[p] = __expf(lrelu(ssv + sdA) - bndA);
        }
        __syncthreads();
        // phase B: gather + accumulate (one uint = 2 bf16 per thread, 256B/wave/neighbor)
        for (int i = 0; i < dc; ++i) {
            float ex = sex[i * 8 + h];
            uint32_t hv = hb[(size_t)sidx[i] * 192 + r * 64 + j];
            denom += ex;
            accx = fmaf(ex, bf2f_lo(hv), accx);
            accy = fmaf(ex, bf2f_hi(hv), accy);
        }
        __syncthreads();
    }
    const float* b = (r == 0) ? b1 : (r == 1) ? b2 : b3;
    float inv = 1.0f / (denom + 1e-16f);
    float ox = accx * inv + b[2 * j];
    float oy = accy * inv + b[2 * j + 1];
    ox = (ox > 0.f) ? ox : 0.f;
    oy = (oy > 0.f) ? oy : 0.f;
    uint32_t packed = (uint32_t)f2bf(ox) | ((uint32_t)f2bf(oy) << 16);
    reinterpret_cast<uint32_t*>(Xc)[(size_t)n * 192 + r * 64 + j] = packed;
}

// ==================== layer 2: linear + branch min/max fused ====================
// blockDim 1024 = 16 nodes (one wave each); Xc is bf16, read as uint
__global__ void k_linear2(const unsigned short* __restrict__ Xc,
                          const float* __restrict__ W1, const float* __restrict__ W2,
                          const float* __restrict__ W3,
                          float* __restrict__ h2, float* __restrict__ M2, int N) {
    __shared__ float redmx[16][3], redmn[16][3];
    int gid = blockIdx.x * 1024 + threadIdx.x;
    int node = gid >> 6;
    int lane = gid & 63;
    int wv = threadIdx.x >> 6;
    float s0 = 0.f, s1 = 0.f, s2 = 0.f;
    if (node < N) {
        const uint32_t* xp = reinterpret_cast<const uint32_t*>(Xc) + (size_t)node * 192;
        const float2* W1v = reinterpret_cast<const float2*>(W1);
        const float2* W2v = reinterpret_cast<const float2*>(W2);
        const float2* W3v = reinterpret_cast<const float2*>(W3);
        #pragma unroll
        for (int j0 = 0; j0 < 192; j0 += 64) {
            uint32_t xv = xp[j0 + lane];
            float x0 = bf2f_lo(xv), x1 = bf2f_hi(xv);
            float2 w1 = W1v[j0 + lane], w2 = W2v[j0 + lane], w3 = W3v[j0 + lane];
            s0 = fmaf(x0, w1.x, s0); s0 = fmaf(x1, w1.y, s0);
            s1 = fmaf(x0, w2.x, s1); s1 = fmaf(x1, w2.y, s1);
            s2 = fmaf(x0, w3.x, s2); s2 = fmaf(x1, w3.y, s2);
        }
    }
    #pragma unroll
    for (int off = 32; off > 0; off >>= 1) {
        s0 += __shfl_down(s0, off);
        s1 += __shfl_down(s1, off);
        s2 += __shfl_down(s2, off);
    }
    if (lane == 0) {
        if (node < N) {
            h2[(size_t)node * 3 + 0] = s0;
            h2[(size_t)node * 3 + 1] = s1;
            h2[(size_t)node * 3 + 2] = s2;
            redmx[wv][0] = s0; redmx[wv][1] = s1; redmx[wv][2] = s2;
            redmn[wv][0] = s0; redmn[wv][1] = s1; redmn[wv][2] = s2;
        } else {
            redmx[wv][0] = redmx[wv][1] = redmx[wv][2] = -INFINITY;
            redmn[wv][0] = redmn[wv][1] = redmn[wv][2] = INFINITY;
        }
    }
    __syncthreads();
    if (threadIdx.x < 3) {
        float m = -INFINITY;
        for (int w2 = 0; w2 < 16; ++w2) m = fmaxf(m, redmx[w2][threadIdx.x]);
        atomicMaxF(&M2[threadIdx.x], m);
    } else if (threadIdx.x < 6) {
        int rr = threadIdx.x - 3;
        float m = INFINITY;
        for (int w2 = 0; w2 < 16; ++w2) m = fminf(m, redmn[w2][rr]);
        atomicMinF(&M2[3 + rr], m);
    }
}

// ==================== layer-2 aggregation + final projection ====================
// 4 lanes per (node, branch); blockDim 192 = 48 pairs = 16 nodes
__global__ __launch_bounds__(192) void k_agg2f(
        const float* __restrict__ h2,
        const int* __restrict__ deg, const int* __restrict__ start,
        const int* __restrict__ csr,
        const float* __restrict__ as1, const float* __restrict__ ad1,
        const float* __restrict__ as2, const float* __restrict__ ad2,
        const float* __restrict__ as3, const float* __restrict__ ad3,
        const float* __restrict__ b1, const float* __restrict__ b2,
        const float* __restrict__ b3,
        const float* __restrict__ M2,
        const float* __restrict__ ln_w, const float* __restrict__ ln_b,
        float* __restrict__ out, int E, int N) {
    __shared__ float ys[48];
    int tl = threadIdx.x;
    int pl = tl >> 2;                 // pair 0..47
    int q  = tl & 3;                  // lane in quad
    int id = blockIdx.x * 48 + pl;
    bool valid = id < 3 * N;
    int n = id / 3;
    int r = id - 3 * n;
    float denom = 0.f, acc = 0.f;
    float a_s = 0.f, sd = 0.f, bound = 0.f, hd = 0.f;
    if (valid) {
        a_s = ((r == 0) ? as1 : (r == 1) ? as2 : as3)[0];
        float a_d = ((r == 0) ? ad1 : (r == 1) ? ad2 : ad3)[0];
        int s0 = start[(size_t)r * N + n];
        int d  = deg[(size_t)r * N + n];
        hd = h2[id];
        sd = a_d * hd;
        bound = lrelu(fmaxf(a_s * M2[r], a_s * M2[3 + r]) + sd);
        const int* cs = csr + (size_t)r * E + s0;
        for (int i = q; i < d; i += 4) {
            float hs = h2[(size_t)cs[i] * 3 + r];
            float e2 = __expf(lrelu(fmaf(a_s, hs, sd)) - bound);
            denom += e2;
            acc = fmaf(e2, hs, acc);
        }
        if (q == 0) {
            float ev = __expf(lrelu(fmaf(a_s, hd, sd)) - bound);
            denom += ev;
            acc = fmaf(ev, hd, acc);
        }
    }
    denom += __shfl_xor(denom, 1); denom += __shfl_xor(denom, 2);
    acc   += __shfl_xor(acc, 1);   acc   += __shfl_xor(acc, 2);
    if (valid && q == 0) {
        float b = ((r == 0) ? b1 : (r == 1) ? b2 : b3)[0];
        ys[pl] = (acc / (denom + 1e-16f) + b) * ln_w[r];
    }
    __syncthreads();
    if (valid && q == 0 && r == 0)
        out[n] = ys[pl] + ys[pl + 1] + ys[pl + 2] + ln_b[0];
}

extern "C" void kernel_launch(void* const* d_in, const int* in_sizes, int n_in,
                              void* d_out, int out_size, void* d_ws, size_t ws_size,
                              hipStream_t stream) {
    const float* X  = (const float*)d_in[0];
    const int*   A1 = (const int*)d_in[1];
    const int*   A2 = (const int*)d_in[2];
    const int*   A3 = (const int*)d_in[3];
    const float* W11 = (const float*)d_in[5];
    const float* as11 = (const float*)d_in[6];
    const float* ad11 = (const float*)d_in[7];
    const float* b11 = (const float*)d_in[8];
    const float* W12 = (const float*)d_in[9];
    const float* as12 = (const float*)d_in[10];
    const float* ad12 = (const float*)d_in[11];
    const float* b12 = (const float*)d_in[12];
    const float* W21 = (const float*)d_in[13];
    const float* as21 = (const float*)d_in[14];
    const float* ad21 = (const float*)d_in[15];
    const float* b21 = (const float*)d_in[16];
    const float* W22 = (const float*)d_in[17];
    const float* as22 = (const float*)d_in[18];
    const float* ad22 = (const float*)d_in[19];
    const float* b22 = (const float*)d_in[20];
    const float* W31 = (const float*)d_in[21];
    const float* as31 = (const float*)d_in[22];
    const float* ad31 = (const float*)d_in[23];
    const float* b31 = (const float*)d_in[24];
    const float* W32 = (const float*)d_in[25];
    const float* as32 = (const float*)d_in[26];
    const float* ad32 = (const float*)d_in[27];
    const float* b32 = (const float*)d_in[28];
    const float* ln_w = (const float*)d_in[29];
    const float* ln_b = (const float*)d_in[30];

    const int N = in_sizes[0] / 64;
    const int E = in_sizes[1] / 2;
    const int total = 3 * N;
    const int nbA = (total + 1023) / 1024;

    // workspace layout
    float* w = (float*)d_ws;
    float* s_src1 = w; w += (size_t)N * 24;
    float* s_dst1 = w; w += (size_t)N * 24;
    float* h2     = w; w += (size_t)N * 3;
    float* Mg1    = w; w += 32;
    float* M2     = w; w += 8;
    unsigned short* h_bf = (unsigned short*)w; w += (size_t)N * 192;  // N*384 bf16
    unsigned short* Xc   = (unsigned short*)w; w += (size_t)N * 192;  // N*384 bf16
    int* iw    = (int*)w;
    int* deg   = iw; iw += (size_t)3 * N;
    int* cnt   = iw; iw += (size_t)3 * N;   // contiguous with deg -> one memset
    int* start = iw; iw += (size_t)3 * N;
    int* bsum  = iw; iw += 1024;
    int* csr   = iw; iw += (size_t)3 * E;

    const int BLK = 256;

    // ---- CSR build (shared by both layers) ----
    hipMemsetAsync(deg, 0, (size_t)6 * N * sizeof(int), stream);
    {
        dim3 grid((E + BLK - 1) / BLK, 3);
        k_deg<<<grid, BLK, 0, stream>>>(A1, A2, A3, deg, E, N);
        k_scanA<<<nbA, 256, 0, stream>>>(deg, start, bsum, total);
        k_scanB<<<1, 256, 0, stream>>>(bsum, nbA, Mg1, M2);
        k_scanC<<<(total + BLK - 1) / BLK, BLK, 0, stream>>>(start, bsum, total, N, E);
        k_scatter<<<grid, BLK, 0, stream>>>(A1, A2, A3, start, cnt, csr, E, N);
    }

    // ---- layer 1 ----
    k_linear1<<<(N + L1_NODES - 1) / L1_NODES, 384, 0, stream>>>(
        X, W11, W21, W31, as11, ad11, as21, ad21, as31, ad31,
        h_bf, s_src1, s_dst1, Mg1, N);
    {
        dim3 grid(N, 3);
        k_agg1<<<grid, 64, 0, stream>>>(h_bf, s_src1, s_dst1, Mg1, deg, start, csr,
                                        b11, b21, b31, Xc, E, N);
    }

    // ---- layer 2 ----
    k_linear2<<<(N + 15) / 16, 1024, 0, stream>>>(Xc, W12, W22, W32, h2, M2, N);
    {
        int nb = (total + 47) / 48;
        k_agg2f<<<nb, 192, 0, stream>>>(
            h2, deg, start, csr,
            as12, ad12, as22, ad22, as32, ad32,
            b12, b22, b32, M2, ln_w, ln_b, (float*)d_out, E, N);
    }
}

// Round 9
// 540.098 us; speedup vs baseline: 35.6996x; 1.1937x over previous
//
#include <hip/hip_runtime.h>
#include <cstdint>
#include <cstddef>

#define NEG_SLOPE 0.2f

__device__ __forceinline__ float lrelu(float v) { return v >= 0.f ? v : NEG_SLOPE * v; }

__device__ __forceinline__ void atomicMaxF(float* addr, float val) {
    if (val >= 0.0f) atomicMax((int*)addr, __float_as_int(val));
    else             atomicMin((unsigned int*)addr, __float_as_uint(val));
}
__device__ __forceinline__ void atomicMinF(float* addr, float val) {
    if (val >= 0.0f) atomicMin((int*)addr, __float_as_int(val));
    else             atomicMax((unsigned int*)addr, __float_as_uint(val));
}

// bf16 pack/unpack (round-to-nearest-even)
__device__ __forceinline__ unsigned short f2bf(float x) {
    union { float f; uint32_t u; } v; v.f = x;
    uint32_t r = v.u + 0x7FFFu + ((v.u >> 16) & 1u);
    return (unsigned short)(r >> 16);
}
__device__ __forceinline__ float bf2f(unsigned short h) {
    union { uint32_t u; float f; } v; v.u = (uint32_t)h << 16;
    return v.f;
}
__device__ __forceinline__ float bf2f_lo(uint32_t u) {
    union { uint32_t u; float f; } v; v.u = u << 16;
    return v.f;
}
__device__ __forceinline__ float bf2f_hi(uint32_t u) {
    union { uint32_t u; float f; } v; v.u = u & 0xFFFF0000u;
    return v.f;
}

// ==================== CSR build ====================
// pass 1: degree count; the atomic's return value IS this edge's slot -> epos
__global__ void k_degpos(const int* __restrict__ A1, const int* __restrict__ A2,
                         const int* __restrict__ A3, int* __restrict__ deg,
                         int* __restrict__ epos, int E, int N) {
    int e = blockIdx.x * blockDim.x + threadIdx.x;
    if (e >= E) return;
    int r = blockIdx.y;
    const int* A = (r == 0) ? A1 : (r == 1) ? A2 : A3;
    int dst = A[E + e];
    epos[(size_t)r * E + e] = atomicAdd(&deg[(size_t)r * N + dst], 1);
}

__global__ void k_scanA(const int* __restrict__ deg, int* __restrict__ start,
                        int* __restrict__ bsum, int total) {
    __shared__ int tmp[256];
    int t = threadIdx.x;
    int base = blockIdx.x * 1024 + t * 4;
    int v[4]; int s = 0;
    #pragma unroll
    for (int k = 0; k < 4; ++k) { v[k] = (base + k < total) ? deg[base + k] : 0; s += v[k]; }
    tmp[t] = s; __syncthreads();
    for (int off = 1; off < 256; off <<= 1) {
        int x = (t >= off) ? tmp[t - off] : 0; __syncthreads();
        tmp[t] += x; __syncthreads();
    }
    int run = tmp[t] - s;
    #pragma unroll
    for (int k = 0; k < 4; ++k) {
        if (base + k < total) start[base + k] = run;
        run += v[k];
    }
    if (t == 255) bsum[blockIdx.x] = tmp[255];
}

// one block; also re-initializes Mg1/M2 (runs before linear kernels in-stream)
__global__ void k_scanB(int* __restrict__ bsum, int nb,
                        float* __restrict__ Mg, float* __restrict__ M2) {
    __shared__ int tmp[256];
    int t = threadIdx.x;
    if (t < 24) Mg[t] = -INFINITY;
    else if (t < 27) M2[t - 24] = -INFINITY;   // M2[0..2] = branch max
    else if (t < 30) M2[t - 24] = INFINITY;    // M2[3..5] = branch min
    int v[4]; int s = 0;
    #pragma unroll
    for (int k = 0; k < 4; ++k) { int i = t * 4 + k; v[k] = (i < nb) ? bsum[i] : 0; s += v[k]; }
    tmp[t] = s; __syncthreads();
    for (int off = 1; off < 256; off <<= 1) {
        int x = (t >= off) ? tmp[t - off] : 0; __syncthreads();
        tmp[t] += x; __syncthreads();
    }
    int run = tmp[t] - s;
    #pragma unroll
    for (int k = 0; k < 4; ++k) {
        int i = t * 4 + k;
        if (i < nb) { int vv = v[k]; bsum[i] = run; run += vv; }
    }
}

__global__ void k_scanC(int* __restrict__ start, const int* __restrict__ bsum,
                        int total, int N, int E) {
    int g = blockIdx.x * blockDim.x + threadIdx.x;
    if (g >= total) return;
    int r = g / N;
    start[g] += bsum[g >> 10] - r * E;
}

// pass 2: no atomics — slot comes from epos
__global__ void k_scatter2(const int* __restrict__ A1, const int* __restrict__ A2,
                           const int* __restrict__ A3,
                           const int* __restrict__ start, const int* __restrict__ epos,
                           int* __restrict__ csr, int E, int N) {
    int e = blockIdx.x * blockDim.x + threadIdx.x;
    if (e >= E) return;
    int r = blockIdx.y;
    const int* A = (r == 0) ? A1 : (r == 1) ? A2 : A3;
    int src = A[e], dst = A[E + e];
    int pos = start[(size_t)r * N + dst] + epos[(size_t)r * E + e];
    csr[(size_t)r * E + pos] = src;
}

// ==================== layer 1: register-W linear + scores + global-max ====================
#define L1_NODES 64
__global__ __launch_bounds__(384) void k_linear1(
        const float* __restrict__ X,
        const float* __restrict__ W1, const float* __restrict__ W2,
        const float* __restrict__ W3,
        const float* __restrict__ as1, const float* __restrict__ ad1,
        const float* __restrict__ as2, const float* __restrict__ ad2,
        const float* __restrict__ as3, const float* __restrict__ ad3,
        unsigned short* __restrict__ h_bf,
        float* __restrict__ s_src, float* __restrict__ s_dst,
        float* __restrict__ Mg, int N) {
    __shared__ float Xs[L1_NODES][64];
    int t = threadIdx.x;
    int n0 = blockIdx.x * L1_NODES;
    {
        const float4* X4 = reinterpret_cast<const float4*>(X);
        float4* Xs4 = reinterpret_cast<float4*>(&Xs[0][0]);
        for (int i = t; i < L1_NODES * 16; i += 384) {
            int nl = i >> 4;
            float4 xv = make_float4(0.f, 0.f, 0.f, 0.f);
            if (n0 + nl < N) xv = X4[(size_t)(n0 + nl) * 16 + (i & 15)];
            Xs4[i] = xv;
        }
    }
    int r = t >> 7, col = t & 127, head = (t >> 4) & 7, c = t & 15;
    const float* Wp = ((r == 0) ? W1 : (r == 1) ? W2 : W3) + col;
    float Wc[64];
    #pragma unroll
    for (int k = 0; k < 64; ++k) Wc[k] = Wp[(size_t)k * 128];
    float as_v = ((r == 0) ? as1 : (r == 1) ? as2 : as3)[head * 16 + c];
    float ad_v = ((r == 0) ? ad1 : (r == 1) ? ad2 : ad3)[head * 16 + c];
    __syncthreads();
    int nmax = min(L1_NODES, N - n0);
    float mgm = -INFINITY;
    int rh = (r << 3) + head;
    for (int n = 0; n < nmax; ++n) {
        const float4* xr = reinterpret_cast<const float4*>(&Xs[n][0]);
        float a0 = 0.f, a1 = 0.f, a2 = 0.f, a3 = 0.f;
        #pragma unroll
        for (int k4 = 0; k4 < 16; ++k4) {
            float4 xv = xr[k4];
            a0 = fmaf(xv.x, Wc[k4 * 4 + 0], a0);
            a1 = fmaf(xv.y, Wc[k4 * 4 + 1], a1);
            a2 = fmaf(xv.z, Wc[k4 * 4 + 2], a2);
            a3 = fmaf(xv.w, Wc[k4 * 4 + 3], a3);
        }
        float acc = (a0 + a1) + (a2 + a3);
        h_bf[(size_t)(n0 + n) * 384 + t] = f2bf(acc);
        float ss = acc * as_v, sd = acc * ad_v;
        ss += __shfl_xor(ss, 1); ss += __shfl_xor(ss, 2);
        ss += __shfl_xor(ss, 4); ss += __shfl_xor(ss, 8);
        sd += __shfl_xor(sd, 1); sd += __shfl_xor(sd, 2);
        sd += __shfl_xor(sd, 4); sd += __shfl_xor(sd, 8);
        if (c == 0) {
            s_src[(size_t)(n0 + n) * 24 + rh] = ss;
            s_dst[(size_t)(n0 + n) * 24 + rh] = sd;
            mgm = fmaxf(mgm, ss);
        }
    }
    if (c == 0) atomicMaxF(&Mg[rh], mgm);
}

// ==================== layer-1 aggregation ====================
// block = (dst n, branch r), 64 threads; each thread owns a uint = 2 bf16 channels
__global__ __launch_bounds__(64) void k_agg1(
        const unsigned short* __restrict__ h_bf,
        const float* __restrict__ s_src, const float* __restrict__ s_dst,
        const float* __restrict__ Mg,
        const int* __restrict__ deg, const int* __restrict__ start,
        const int* __restrict__ csr,
        const float* __restrict__ b1, const float* __restrict__ b2,
        const float* __restrict__ b3,
        unsigned short* __restrict__ Xc, int E, int N) {
    __shared__ int sidx[64];
    __shared__ float sex[64 * 8];
    int n = blockIdx.x;
    int r = blockIdx.y;
    int j = threadIdx.x;              // uint channel-pair index 0..63
    int h = j >> 3;                   // head (16 ch = 8 uints per head)
    int rh = r * 8 + h;
    int s0 = start[(size_t)r * N + n];
    int d  = deg[(size_t)r * N + n];
    const uint32_t* hb = reinterpret_cast<const uint32_t*>(h_bf);
    float sd = s_dst[(size_t)n * 24 + rh];
    float bound = lrelu(Mg[rh] + sd);
    float ex0 = __expf(lrelu(s_src[(size_t)n * 24 + rh] + sd) - bound);
    float denom = ex0;
    uint32_t hv0 = hb[(size_t)n * 192 + r * 64 + j];
    float accx = ex0 * bf2f_lo(hv0);
    float accy = ex0 * bf2f_hi(hv0);
    int hA = j & 7;
    float sdA = s_dst[(size_t)n * 24 + r * 8 + hA];
    float bndA = lrelu(Mg[r * 8 + hA] + sdA);
    const int* cs = csr + (size_t)r * E + s0;
    for (int c0 = 0; c0 < d; c0 += 64) {
        int dc = min(64, d - c0);
        if (j < dc) sidx[j] = cs[c0 + j];
        __syncthreads();
        // phase A: one exp per (neighbor, head)
        for (int p = j; p < dc * 8; p += 64) {
            int i = p >> 3;
            float ssv = s_src[(size_t)sidx[i] * 24 + r * 8 + hA];
            sex[p] = __expf(lrelu(ssv + sdA) - bndA);
        }
        __syncthreads();
        // phase B: gather + accumulate (one uint = 2 bf16 per thread, 256B/wave/neighbor)
        for (int i = 0; i < dc; ++i) {
            float ex = sex[i * 8 + h];
            uint32_t hv = hb[(size_t)sidx[i] * 192 + r * 64 + j];
            denom += ex;
            accx = fmaf(ex, bf2f_lo(hv), accx);
            accy = fmaf(ex, bf2f_hi(hv), accy);
        }
        __syncthreads();
    }
    const float* b = (r == 0) ? b1 : (r == 1) ? b2 : b3;
    float inv = 1.0f / (denom + 1e-16f);
    float ox = accx * inv + b[2 * j];
    float oy = accy * inv + b[2 * j + 1];
    ox = (ox > 0.f) ? ox : 0.f;
    oy = (oy > 0.f) ? oy : 0.f;
    uint32_t packed = (uint32_t)f2bf(ox) | ((uint32_t)f2bf(oy) << 16);
    reinterpret_cast<uint32_t*>(Xc)[(size_t)n * 192 + r * 64 + j] = packed;
}

// ==================== layer 2: linear + branch min/max fused ====================
// blockDim 1024 = 16 nodes (one wave each); Xc is bf16, read as uint
__global__ void k_linear2(const unsigned short* __restrict__ Xc,
                          const float* __restrict__ W1, const float* __restrict__ W2,
                          const float* __restrict__ W3,
                          float* __restrict__ h2, float* __restrict__ M2, int N) {
    __shared__ float redmx[16][3], redmn[16][3];
    int gid = blockIdx.x * 1024 + threadIdx.x;
    int node = gid >> 6;
    int lane = gid & 63;
    int wv = threadIdx.x >> 6;
    float s0 = 0.f, s1 = 0.f, s2 = 0.f;
    if (node < N) {
        const uint32_t* xp = reinterpret_cast<const uint32_t*>(Xc) + (size_t)node * 192;
        const float2* W1v = reinterpret_cast<const float2*>(W1);
        const float2* W2v = reinterpret_cast<const float2*>(W2);
        const float2* W3v = reinterpret_cast<const float2*>(W3);
        #pragma unroll
        for (int j0 = 0; j0 < 192; j0 += 64) {
            uint32_t xv = xp[j0 + lane];
            float x0 = bf2f_lo(xv), x1 = bf2f_hi(xv);
            float2 w1 = W1v[j0 + lane], w2 = W2v[j0 + lane], w3 = W3v[j0 + lane];
            s0 = fmaf(x0, w1.x, s0); s0 = fmaf(x1, w1.y, s0);
            s1 = fmaf(x0, w2.x, s1); s1 = fmaf(x1, w2.y, s1);
            s2 = fmaf(x0, w3.x, s2); s2 = fmaf(x1, w3.y, s2);
        }
    }
    #pragma unroll
    for (int off = 32; off > 0; off >>= 1) {
        s0 += __shfl_down(s0, off);
        s1 += __shfl_down(s1, off);
        s2 += __shfl_down(s2, off);
    }
    if (lane == 0) {
        if (node < N) {
            h2[(size_t)node * 3 + 0] = s0;
            h2[(size_t)node * 3 + 1] = s1;
            h2[(size_t)node * 3 + 2] = s2;
            redmx[wv][0] = s0; redmx[wv][1] = s1; redmx[wv][2] = s2;
            redmn[wv][0] = s0; redmn[wv][1] = s1; redmn[wv][2] = s2;
        } else {
            redmx[wv][0] = redmx[wv][1] = redmx[wv][2] = -INFINITY;
            redmn[wv][0] = redmn[wv][1] = redmn[wv][2] = INFINITY;
        }
    }
    __syncthreads();
    if (threadIdx.x < 3) {
        float m = -INFINITY;
        for (int w2 = 0; w2 < 16; ++w2) m = fmaxf(m, redmx[w2][threadIdx.x]);
        atomicMaxF(&M2[threadIdx.x], m);
    } else if (threadIdx.x < 6) {
        int rr = threadIdx.x - 3;
        float m = INFINITY;
        for (int w2 = 0; w2 < 16; ++w2) m = fminf(m, redmn[w2][rr]);
        atomicMinF(&M2[3 + rr], m);
    }
}

// ==================== layer-2 aggregation + final projection ====================
// 8 lanes per (node, branch); blockDim 384 = 48 units = 16 nodes
__global__ __launch_bounds__(384) void k_agg2f(
        const float* __restrict__ h2,
        const int* __restrict__ deg, const int* __restrict__ start,
        const int* __restrict__ csr,
        const float* __restrict__ as1, const float* __restrict__ ad1,
        const float* __restrict__ as2, const float* __restrict__ ad2,
        const float* __restrict__ as3, const float* __restrict__ ad3,
        const float* __restrict__ b1, const float* __restrict__ b2,
        const float* __restrict__ b3,
        const float* __restrict__ M2,
        const float* __restrict__ ln_w, const float* __restrict__ ln_b,
        float* __restrict__ out, int E, int N) {
    __shared__ float ys[48];
    int tl = threadIdx.x;
    int pl = tl >> 3;                 // unit 0..47
    int q  = tl & 7;                  // lane in unit
    int id = blockIdx.x * 48 + pl;
    bool valid = id < 3 * N;
    int n = id / 3;
    int r = id - 3 * n;
    float denom = 0.f, acc = 0.f;
    if (valid) {
        float a_s = ((r == 0) ? as1 : (r == 1) ? as2 : as3)[0];
        float a_d = ((r == 0) ? ad1 : (r == 1) ? ad2 : ad3)[0];
        int s0 = start[(size_t)r * N + n];
        int d  = deg[(size_t)r * N + n];
        float hd = h2[id];
        float sd = a_d * hd;
        float bound = lrelu(fmaxf(a_s * M2[r], a_s * M2[3 + r]) + sd);
        const int* cs = csr + (size_t)r * E + s0;
        for (int i = q; i < d; i += 8) {
            float hs = h2[(size_t)cs[i] * 3 + r];
            float e2 = __expf(lrelu(fmaf(a_s, hs, sd)) - bound);
            denom += e2;
            acc = fmaf(e2, hs, acc);
        }
        if (q == 0) {
            float ev = __expf(lrelu(fmaf(a_s, hd, sd)) - bound);
            denom += ev;
            acc = fmaf(ev, hd, acc);
        }
    }
    denom += __shfl_xor(denom, 1); denom += __shfl_xor(denom, 2); denom += __shfl_xor(denom, 4);
    acc   += __shfl_xor(acc, 1);   acc   += __shfl_xor(acc, 2);   acc   += __shfl_xor(acc, 4);
    if (valid && q == 0) {
        float b = ((r == 0) ? b1 : (r == 1) ? b2 : b3)[0];
        ys[pl] = (acc / (denom + 1e-16f) + b) * ln_w[r];
    }
    __syncthreads();
    if (valid && q == 0 && r == 0)
        out[n] = ys[pl] + ys[pl + 1] + ys[pl + 2] + ln_b[0];
}

extern "C" void kernel_launch(void* const* d_in, const int* in_sizes, int n_in,
                              void* d_out, int out_size, void* d_ws, size_t ws_size,
                              hipStream_t stream) {
    const float* X  = (const float*)d_in[0];
    const int*   A1 = (const int*)d_in[1];
    const int*   A2 = (const int*)d_in[2];
    const int*   A3 = (const int*)d_in[3];
    const float* W11 = (const float*)d_in[5];
    const float* as11 = (const float*)d_in[6];
    const float* ad11 = (const float*)d_in[7];
    const float* b11 = (const float*)d_in[8];
    const float* W12 = (const float*)d_in[9];
    const float* as12 = (const float*)d_in[10];
    const float* ad12 = (const float*)d_in[11];
    const float* b12 = (const float*)d_in[12];
    const float* W21 = (const float*)d_in[13];
    const float* as21 = (const float*)d_in[14];
    const float* ad21 = (const float*)d_in[15];
    const float* b21 = (const float*)d_in[16];
    const float* W22 = (const float*)d_in[17];
    const float* as22 = (const float*)d_in[18];
    const float* ad22 = (const float*)d_in[19];
    const float* b22 = (const float*)d_in[20];
    const float* W31 = (const float*)d_in[21];
    const float* as31 = (const float*)d_in[22];
    const float* ad31 = (const float*)d_in[23];
    const float* b31 = (const float*)d_in[24];
    const float* W32 = (const float*)d_in[25];
    const float* as32 = (const float*)d_in[26];
    const float* ad32 = (const float*)d_in[27];
    const float* b32 = (const float*)d_in[28];
    const float* ln_w = (const float*)d_in[29];
    const float* ln_b = (const float*)d_in[30];

    const int N = in_sizes[0] / 64;
    const int E = in_sizes[1] / 2;
    const int total = 3 * N;
    const int nbA = (total + 1023) / 1024;

    // workspace layout
    float* w = (float*)d_ws;
    float* s_src1 = w; w += (size_t)N * 24;
    float* s_dst1 = w; w += (size_t)N * 24;
    float* h2     = w; w += (size_t)N * 3;
    float* Mg1    = w; w += 32;
    float* M2     = w; w += 8;
    unsigned short* h_bf = (unsigned short*)w; w += (size_t)N * 192;  // N*384 bf16
    unsigned short* Xc   = (unsigned short*)w; w += (size_t)N * 192;  // N*384 bf16
    int* iw    = (int*)w;
    int* deg   = iw; iw += (size_t)3 * N;
    int* start = iw; iw += (size_t)3 * N;
    int* bsum  = iw; iw += 1024;
    int* epos  = iw; iw += (size_t)3 * E;
    int* csr   = iw; iw += (size_t)3 * E;

    const int BLK = 256;

    // ---- CSR build (shared by both layers) ----
    hipMemsetAsync(deg, 0, (size_t)3 * N * sizeof(int), stream);
    {
        dim3 grid((E + BLK - 1) / BLK, 3);
        k_degpos<<<grid, BLK, 0, stream>>>(A1, A2, A3, deg, epos, E, N);
        k_scanA<<<nbA, 256, 0, stream>>>(deg, start, bsum, total);
        k_scanB<<<1, 256, 0, stream>>>(bsum, nbA, Mg1, M2);
        k_scanC<<<(total + BLK - 1) / BLK, BLK, 0, stream>>>(start, bsum, total, N, E);
        k_scatter2<<<grid, BLK, 0, stream>>>(A1, A2, A3, start, epos, csr, E, N);
    }

    // ---- layer 1 ----
    k_linear1<<<(N + L1_NODES - 1) / L1_NODES, 384, 0, stream>>>(
        X, W11, W21, W31, as11, ad11, as21, ad21, as31, ad31,
        h_bf, s_src1, s_dst1, Mg1, N);
    {
        dim3 grid(N, 3);
        k_agg1<<<grid, 64, 0, stream>>>(h_bf, s_src1, s_dst1, Mg1, deg, start, csr,
                                        b11, b21, b31, Xc, E, N);
    }

    // ---- layer 2 ----
    k_linear2<<<(N + 15) / 16, 1024, 0, stream>>>(Xc, W12, W22, W32, h2, M2, N);
    {
        int nb = (total + 47) / 48;
        k_agg2f<<<nb, 384, 0, stream>>>(
            h2, deg, start, csr,
            as12, ad12, as22, ad22, as32, ad32,
            b12, b22, b32, M2, ln_w, ln_b, (float*)d_out, E, N);
    }
}

// Round 10
// 453.773 us; speedup vs baseline: 42.4911x; 1.1902x over previous
//
#include <hip/hip_runtime.h>
#include <cstdint>
#include <cstddef>

#define NEG_SLOPE 0.2f

__device__ __forceinline__ float lrelu(float v) { return v >= 0.f ? v : NEG_SLOPE * v; }

// bf16 pack/unpack (round-to-nearest-even)
__device__ __forceinline__ unsigned short f2bf(float x) {
    union { float f; uint32_t u; } v; v.f = x;
    uint32_t r = v.u + 0x7FFFu + ((v.u >> 16) & 1u);
    return (unsigned short)(r >> 16);
}
__device__ __forceinline__ float bf2f(unsigned short h) {
    union { uint32_t u; float f; } v; v.u = (uint32_t)h << 16;
    return v.f;
}
__device__ __forceinline__ float bf2f_lo(uint32_t u) {
    union { uint32_t u; float f; } v; v.u = u << 16;
    return v.f;
}
__device__ __forceinline__ float bf2f_hi(uint32_t u) {
    union { uint32_t u; float f; } v; v.u = u & 0xFFFF0000u;
    return v.f;
}

// ==================== CSR build ====================
// pass 1: 8-way-spread degree count; atomic return = slot within (dst, copy k)
__global__ void k_degpos8(const int* __restrict__ A1, const int* __restrict__ A2,
                          const int* __restrict__ A3, int* __restrict__ deg8,
                          int* __restrict__ epos, int E, int N) {
    int e = blockIdx.x * blockDim.x + threadIdx.x;
    if (e >= E) return;
    int r = blockIdx.y;
    int k = blockIdx.x & 7;
    const int* A = (r == 0) ? A1 : (r == 1) ? A2 : A3;
    int dst = A[E + e];
    epos[(size_t)r * E + e] = atomicAdd(&deg8[(size_t)((r << 3) + k) * N + dst], 1);
}

// scan A: fold 8 sub-histograms -> deg + per-copy local offsets (startk, pre-base),
// plus block-local exclusive scan of deg -> start, block sums -> bsum
__global__ void k_scanA2(const int* __restrict__ deg8, int* __restrict__ deg,
                         int* __restrict__ startk, int* __restrict__ start,
                         int* __restrict__ bsum, int total, int N) {
    __shared__ int tmp[256];
    int t = threadIdx.x;
    int base = blockIdx.x * 1024 + t * 4;
    int v[4]; int s = 0;
    #pragma unroll
    for (int m = 0; m < 4; ++m) {
        int g = base + m;
        int sum8 = 0;
        if (g < total) {
            int r = g / N;
            int n = g - r * N;
            #pragma unroll
            for (int k = 0; k < 8; ++k) {
                size_t idx = (size_t)((r << 3) + k) * N + n;
                int dv = deg8[idx];
                startk[idx] = sum8;
                sum8 += dv;
            }
            deg[g] = sum8;
        }
        v[m] = sum8; s += sum8;
    }
    tmp[t] = s; __syncthreads();
    for (int off = 1; off < 256; off <<= 1) {
        int x = (t >= off) ? tmp[t - off] : 0; __syncthreads();
        tmp[t] += x; __syncthreads();
    }
    int run = tmp[t] - s;
    #pragma unroll
    for (int m = 0; m < 4; ++m) {
        if (base + m < total) start[base + m] = run;
        run += v[m];
    }
    if (t == 255) bsum[blockIdx.x] = tmp[255];
}

// scan B: one block, exclusive scan of block sums
__global__ void k_scanB(int* __restrict__ bsum, int nb) {
    __shared__ int tmp[256];
    int t = threadIdx.x;
    int v[4]; int s = 0;
    #pragma unroll
    for (int k = 0; k < 4; ++k) { int i = t * 4 + k; v[k] = (i < nb) ? bsum[i] : 0; s += v[k]; }
    tmp[t] = s; __syncthreads();
    for (int off = 1; off < 256; off <<= 1) {
        int x = (t >= off) ? tmp[t - off] : 0; __syncthreads();
        tmp[t] += x; __syncthreads();
    }
    int run = tmp[t] - s;
    #pragma unroll
    for (int k = 0; k < 4; ++k) {
        int i = t * 4 + k;
        if (i < nb) { int vv = v[k]; bsum[i] = run; run += vv; }
    }
}

// scan C: finalize global base; push base into the 8 startk copies
__global__ void k_scanC2(int* __restrict__ start, const int* __restrict__ bsum,
                         int* __restrict__ startk, int total, int N, int E) {
    int g = blockIdx.x * blockDim.x + threadIdx.x;
    if (g >= total) return;
    int r = g / N;
    int n = g - r * N;
    int base = start[g] + bsum[g >> 10] - r * E;
    start[g] = base;
    #pragma unroll
    for (int k = 0; k < 8; ++k)
        startk[(size_t)((r << 3) + k) * N + n] += base;
}

// pass 2: no atomics — pos = startk[k][dst] + epos
__global__ void k_scatter2(const int* __restrict__ A1, const int* __restrict__ A2,
                           const int* __restrict__ A3,
                           const int* __restrict__ startk, const int* __restrict__ epos,
                           int* __restrict__ csr, int E, int N) {
    int e = blockIdx.x * blockDim.x + threadIdx.x;
    if (e >= E) return;
    int r = blockIdx.y;
    int k = blockIdx.x & 7;
    const int* A = (r == 0) ? A1 : (r == 1) ? A2 : A3;
    int src = A[e], dst = A[E + e];
    int pos = startk[(size_t)((r << 3) + k) * N + dst] + epos[(size_t)r * E + e];
    csr[(size_t)r * E + pos] = src;
}

// ==================== layer 1: register-W linear + scores ====================
#define L1_NODES 64
__global__ __launch_bounds__(384) void k_linear1(
        const float* __restrict__ X,
        const float* __restrict__ W1, const float* __restrict__ W2,
        const float* __restrict__ W3,
        const float* __restrict__ as1, const float* __restrict__ ad1,
        const float* __restrict__ as2, const float* __restrict__ ad2,
        const float* __restrict__ as3, const float* __restrict__ ad3,
        unsigned short* __restrict__ h_bf,
        float* __restrict__ s_src, float* __restrict__ s_dst, int N) {
    __shared__ float Xs[L1_NODES][64];
    int t = threadIdx.x;
    int n0 = blockIdx.x * L1_NODES;
    {
        const float4* X4 = reinterpret_cast<const float4*>(X);
        float4* Xs4 = reinterpret_cast<float4*>(&Xs[0][0]);
        for (int i = t; i < L1_NODES * 16; i += 384) {
            int nl = i >> 4;
            float4 xv = make_float4(0.f, 0.f, 0.f, 0.f);
            if (n0 + nl < N) xv = X4[(size_t)(n0 + nl) * 16 + (i & 15)];
            Xs4[i] = xv;
        }
    }
    int r = t >> 7, col = t & 127, head = (t >> 4) & 7, c = t & 15;
    const float* Wp = ((r == 0) ? W1 : (r == 1) ? W2 : W3) + col;
    float Wc[64];
    #pragma unroll
    for (int k = 0; k < 64; ++k) Wc[k] = Wp[(size_t)k * 128];
    float as_v = ((r == 0) ? as1 : (r == 1) ? as2 : as3)[head * 16 + c];
    float ad_v = ((r == 0) ? ad1 : (r == 1) ? ad2 : ad3)[head * 16 + c];
    __syncthreads();
    int nmax = min(L1_NODES, N - n0);
    int rh = (r << 3) + head;
    for (int n = 0; n < nmax; ++n) {
        const float4* xr = reinterpret_cast<const float4*>(&Xs[n][0]);
        float a0 = 0.f, a1 = 0.f, a2 = 0.f, a3 = 0.f;
        #pragma unroll
        for (int k4 = 0; k4 < 16; ++k4) {
            float4 xv = xr[k4];
            a0 = fmaf(xv.x, Wc[k4 * 4 + 0], a0);
            a1 = fmaf(xv.y, Wc[k4 * 4 + 1], a1);
            a2 = fmaf(xv.z, Wc[k4 * 4 + 2], a2);
            a3 = fmaf(xv.w, Wc[k4 * 4 + 3], a3);
        }
        float acc = (a0 + a1) + (a2 + a3);
        h_bf[(size_t)(n0 + n) * 384 + t] = f2bf(acc);
        float ss = acc * as_v, sd = acc * ad_v;
        ss += __shfl_xor(ss, 1); ss += __shfl_xor(ss, 2);
        ss += __shfl_xor(ss, 4); ss += __shfl_xor(ss, 8);
        sd += __shfl_xor(sd, 1); sd += __shfl_xor(sd, 2);
        sd += __shfl_xor(sd, 4); sd += __shfl_xor(sd, 8);
        if (c == 0) {
            s_src[(size_t)(n0 + n) * 24 + rh] = ss;
            s_dst[(size_t)(n0 + n) * 24 + rh] = sd;
        }
    }
}

// ==================== layer-1 aggregation (unstabilized exp: |s|<~3, fp32-safe) ====
__global__ __launch_bounds__(64) void k_agg1(
        const unsigned short* __restrict__ h_bf,
        const float* __restrict__ s_src, const float* __restrict__ s_dst,
        const int* __restrict__ deg, const int* __restrict__ start,
        const int* __restrict__ csr,
        const float* __restrict__ b1, const float* __restrict__ b2,
        const float* __restrict__ b3,
        unsigned short* __restrict__ Xc, int E, int N) {
    __shared__ int sidx[64];
    __shared__ float sex[64 * 8];
    int n = blockIdx.x;
    int r = blockIdx.y;
    int j = threadIdx.x;              // uint channel-pair index 0..63
    int h = j >> 3;                   // head (16 ch = 8 uints per head)
    int rh = r * 8 + h;
    int s0 = start[(size_t)r * N + n];
    int d  = deg[(size_t)r * N + n];
    const uint32_t* hb = reinterpret_cast<const uint32_t*>(h_bf);
    float sd = s_dst[(size_t)n * 24 + rh];
    float ex0 = __expf(lrelu(s_src[(size_t)n * 24 + rh] + sd));
    float denom = ex0;
    uint32_t hv0 = hb[(size_t)n * 192 + r * 64 + j];
    float accx = ex0 * bf2f_lo(hv0);
    float accy = ex0 * bf2f_hi(hv0);
    int hA = j & 7;
    float sdA = s_dst[(size_t)n * 24 + r * 8 + hA];
    const int* cs = csr + (size_t)r * E + s0;
    for (int c0 = 0; c0 < d; c0 += 64) {
        int dc = min(64, d - c0);
        if (j < dc) sidx[j] = cs[c0 + j];
        __syncthreads();
        for (int p = j; p < dc * 8; p += 64) {
            int i = p >> 3;
            float ssv = s_src[(size_t)sidx[i] * 24 + r * 8 + hA];
            sex[p] = __expf(lrelu(ssv + sdA));
        }
        __syncthreads();
        for (int i = 0; i < dc; ++i) {
            float ex = sex[i * 8 + h];
            uint32_t hv = hb[(size_t)sidx[i] * 192 + r * 64 + j];
            denom += ex;
            accx = fmaf(ex, bf2f_lo(hv), accx);
            accy = fmaf(ex, bf2f_hi(hv), accy);
        }
        __syncthreads();
    }
    const float* b = (r == 0) ? b1 : (r == 1) ? b2 : b3;
    float inv = 1.0f / (denom + 1e-16f);
    float ox = accx * inv + b[2 * j];
    float oy = accy * inv + b[2 * j + 1];
    ox = (ox > 0.f) ? ox : 0.f;
    oy = (oy > 0.f) ? oy : 0.f;
    uint32_t packed = (uint32_t)f2bf(ox) | ((uint32_t)f2bf(oy) << 16);
    reinterpret_cast<uint32_t*>(Xc)[(size_t)n * 192 + r * 64 + j] = packed;
}

// ==================== layer 2: linear ====================
__global__ void k_linear2(const unsigned short* __restrict__ Xc,
                          const float* __restrict__ W1, const float* __restrict__ W2,
                          const float* __restrict__ W3,
                          float* __restrict__ h2, int N) {
    int gid = blockIdx.x * 1024 + threadIdx.x;
    int node = gid >> 6;
    int lane = gid & 63;
    if (node >= N) return;
    const uint32_t* xp = reinterpret_cast<const uint32_t*>(Xc) + (size_t)node * 192;
    const float2* W1v = reinterpret_cast<const float2*>(W1);
    const float2* W2v = reinterpret_cast<const float2*>(W2);
    const float2* W3v = reinterpret_cast<const float2*>(W3);
    float s0 = 0.f, s1 = 0.f, s2 = 0.f;
    #pragma unroll
    for (int j0 = 0; j0 < 192; j0 += 64) {
        uint32_t xv = xp[j0 + lane];
        float x0 = bf2f_lo(xv), x1 = bf2f_hi(xv);
        float2 w1 = W1v[j0 + lane], w2 = W2v[j0 + lane], w3 = W3v[j0 + lane];
        s0 = fmaf(x0, w1.x, s0); s0 = fmaf(x1, w1.y, s0);
        s1 = fmaf(x0, w2.x, s1); s1 = fmaf(x1, w2.y, s1);
        s2 = fmaf(x0, w3.x, s2); s2 = fmaf(x1, w3.y, s2);
    }
    #pragma unroll
    for (int off = 32; off > 0; off >>= 1) {
        s0 += __shfl_down(s0, off);
        s1 += __shfl_down(s1, off);
        s2 += __shfl_down(s2, off);
    }
    if (lane == 0) {
        h2[(size_t)node * 3 + 0] = s0;
        h2[(size_t)node * 3 + 1] = s1;
        h2[(size_t)node * 3 + 2] = s2;
    }
}

// ==================== layer-2 aggregation + final projection ====================
// 8 lanes per (node, branch); blockDim 384 = 48 units = 16 nodes
__global__ __launch_bounds__(384) void k_agg2f(
        const float* __restrict__ h2,
        const int* __restrict__ deg, const int* __restrict__ start,
        const int* __restrict__ csr,
        const float* __restrict__ as1, const float* __restrict__ ad1,
        const float* __restrict__ as2, const float* __restrict__ ad2,
        const float* __restrict__ as3, const float* __restrict__ ad3,
        const float* __restrict__ b1, const float* __restrict__ b2,
        const float* __restrict__ b3,
        const float* __restrict__ ln_w, const float* __restrict__ ln_b,
        float* __restrict__ out, int E, int N) {
    __shared__ float ys[48];
    int tl = threadIdx.x;
    int pl = tl >> 3;                 // unit 0..47
    int q  = tl & 7;                  // lane in unit
    int id = blockIdx.x * 48 + pl;
    bool valid = id < 3 * N;
    int n = id / 3;
    int r = id - 3 * n;
    float denom = 0.f, acc = 0.f;
    if (valid) {
        float a_s = ((r == 0) ? as1 : (r == 1) ? as2 : as3)[0];
        float a_d = ((r == 0) ? ad1 : (r == 1) ? ad2 : ad3)[0];
        int s0 = start[(size_t)r * N + n];
        int d  = deg[(size_t)r * N + n];
        float hd = h2[id];
        float sd = a_d * hd;
        const int* cs = csr + (size_t)r * E + s0;
        for (int i = q; i < d; i += 8) {
            float hs = h2[(size_t)cs[i] * 3 + r];
            float e2 = __expf(lrelu(fmaf(a_s, hs, sd)));
            denom += e2;
            acc = fmaf(e2, hs, acc);
        }
        if (q == 0) {
            float ev = __expf(lrelu(fmaf(a_s, hd, sd)));
            denom += ev;
            acc = fmaf(ev, hd, acc);
        }
    }
    denom += __shfl_xor(denom, 1); denom += __shfl_xor(denom, 2); denom += __shfl_xor(denom, 4);
    acc   += __shfl_xor(acc, 1);   acc   += __shfl_xor(acc, 2);   acc   += __shfl_xor(acc, 4);
    if (valid && q == 0) {
        float b = ((r == 0) ? b1 : (r == 1) ? b2 : b3)[0];
        ys[pl] = (acc / (denom + 1e-16f) + b) * ln_w[r];
    }
    __syncthreads();
    if (valid && q == 0 && r == 0)
        out[n] = ys[pl] + ys[pl + 1] + ys[pl + 2] + ln_b[0];
}

extern "C" void kernel_launch(void* const* d_in, const int* in_sizes, int n_in,
                              void* d_out, int out_size, void* d_ws, size_t ws_size,
                              hipStream_t stream) {
    const float* X  = (const float*)d_in[0];
    const int*   A1 = (const int*)d_in[1];
    const int*   A2 = (const int*)d_in[2];
    const int*   A3 = (const int*)d_in[3];
    const float* W11 = (const float*)d_in[5];
    const float* as11 = (const float*)d_in[6];
    const float* ad11 = (const float*)d_in[7];
    const float* b11 = (const float*)d_in[8];
    const float* W12 = (const float*)d_in[9];
    const float* as12 = (const float*)d_in[10];
    const float* ad12 = (const float*)d_in[11];
    const float* b12 = (const float*)d_in[12];
    const float* W21 = (const float*)d_in[13];
    const float* as21 = (const float*)d_in[14];
    const float* ad21 = (const float*)d_in[15];
    const float* b21 = (const float*)d_in[16];
    const float* W22 = (const float*)d_in[17];
    const float* as22 = (const float*)d_in[18];
    const float* ad22 = (const float*)d_in[19];
    const float* b22 = (const float*)d_in[20];
    const float* W31 = (const float*)d_in[21];
    const float* as31 = (const float*)d_in[22];
    const float* ad31 = (const float*)d_in[23];
    const float* b31 = (const float*)d_in[24];
    const float* W32 = (const float*)d_in[25];
    const float* as32 = (const float*)d_in[26];
    const float* ad32 = (const float*)d_in[27];
    const float* b32 = (const float*)d_in[28];
    const float* ln_w = (const float*)d_in[29];
    const float* ln_b = (const float*)d_in[30];

    const int N = in_sizes[0] / 64;
    const int E = in_sizes[1] / 2;
    const int total = 3 * N;
    const int nbA = (total + 1023) / 1024;

    // workspace layout
    float* w = (float*)d_ws;
    float* s_src1 = w; w += (size_t)N * 24;
    float* s_dst1 = w; w += (size_t)N * 24;
    float* h2     = w; w += (size_t)N * 3;
    unsigned short* h_bf = (unsigned short*)w; w += (size_t)N * 192;  // N*384 bf16
    unsigned short* Xc   = (unsigned short*)w; w += (size_t)N * 192;  // N*384 bf16
    int* iw     = (int*)w;
    int* deg    = iw; iw += (size_t)3 * N;
    int* start  = iw; iw += (size_t)3 * N;
    int* bsum   = iw; iw += 1024;
    int* deg8   = iw; iw += (size_t)24 * N;
    int* startk = iw; iw += (size_t)24 * N;
    int* epos   = iw; iw += (size_t)3 * E;
    int* csr    = iw; iw += (size_t)3 * E;

    const int BLK = 256;

    // ---- CSR build (shared by both layers) ----
    hipMemsetAsync(deg8, 0, (size_t)24 * N * sizeof(int), stream);
    {
        dim3 grid((E + BLK - 1) / BLK, 3);
        k_degpos8<<<grid, BLK, 0, stream>>>(A1, A2, A3, deg8, epos, E, N);
        k_scanA2<<<nbA, 256, 0, stream>>>(deg8, deg, startk, start, bsum, total, N);
        k_scanB<<<1, 256, 0, stream>>>(bsum, nbA);
        k_scanC2<<<(total + BLK - 1) / BLK, BLK, 0, stream>>>(start, bsum, startk, total, N, E);
        k_scatter2<<<grid, BLK, 0, stream>>>(A1, A2, A3, startk, epos, csr, E, N);
    }

    // ---- layer 1 ----
    k_linear1<<<(N + L1_NODES - 1) / L1_NODES, 384, 0, stream>>>(
        X, W11, W21, W31, as11, ad11, as21, ad21, as31, ad31,
        h_bf, s_src1, s_dst1, N);
    {
        dim3 grid(N, 3);
        k_agg1<<<grid, 64, 0, stream>>>(h_bf, s_src1, s_dst1, deg, start, csr,
                                        b11, b21, b31, Xc, E, N);
    }

    // ---- layer 2 ----
    k_linear2<<<(N + 15) / 16, 1024, 0, stream>>>(Xc, W12, W22, W32, h2, N);
    {
        int nb = (total + 47) / 48;
        k_agg2f<<<nb, 384, 0, stream>>>(
            h2, deg, start, csr,
            as12, ad12, as22, ad22, as32, ad32,
            b12, b22, b32, ln_w, ln_b, (float*)d_out, E, N);
    }
}